// Round 2
// baseline (6593.948 us; speedup 1.0000x reference)
//
#include <hip/hip_runtime.h>

#define T_STEPS 256
#define BATCH   128
#define OBSD    512
#define HID     1024
#define GH      4096
#define ACTD    18
#define TBROWS  (T_STEPS*BATCH)   // 32768
#define NWG     128               // scan workgroups (2 batch halves x 64 j-slices)
#define JG      16                // hidden units per scan WG
#define WHROWS  64                // 4 gates * JG
#define WHPAD   1032              // 1024 + 8 (bank-conflict pad)

typedef __bf16 bf16x8_t __attribute__((ext_vector_type(8)));
typedef float  f32x4_t  __attribute__((ext_vector_type(4)));

__device__ __forceinline__ ushort f2bf(float f) {
  unsigned u = __builtin_bit_cast(unsigned, f);
  u += 0x7fffu + ((u >> 16) & 1u);          // RNE
  return (ushort)(u >> 16);
}
__device__ __forceinline__ float bf2f(ushort s) {
  return __builtin_bit_cast(float, ((unsigned)s) << 16);
}
__device__ __forceinline__ f32x4_t mfma16(bf16x8_t a, bf16x8_t b, f32x4_t c) {
  return __builtin_amdgcn_mfma_f32_16x16x32_bf16(a, b, c, 0, 0, 0);
}
__device__ __forceinline__ void gl_lds16(const void* g, void* l) {
  __builtin_amdgcn_global_load_lds(
      (__attribute__((address_space(1))) void*)(g),
      (__attribute__((address_space(3))) void*)(l), 16, 0, 0);
}
__device__ __forceinline__ float sigm(float x) { return 1.f / (1.f + __expf(-x)); }

// ---------------- cast f32 -> bf16 ----------------
__global__ void cast_bf16_kernel(const float* __restrict__ in, ushort* __restrict__ out, int n4) {
  int i = blockIdx.x * blockDim.x + threadIdx.x;
  int stride = gridDim.x * blockDim.x;
  for (; i < n4; i += stride) {
    float4 v = reinterpret_cast<const float4*>(in)[i];
    ushort4 o;
    o.x = f2bf(v.x); o.y = f2bf(v.y); o.z = f2bf(v.z); o.w = f2bf(v.w);
    reinterpret_cast<ushort4*>(out)[i] = o;
  }
}

// ---------------- bf16 GEMM: C = act(A @ Bt^T + bias1 [+ bias2]) ----------------
// A: (M,K) bf16 row-major; Bt: (N,K) bf16 row-major; C: (M,N) bf16.
// 128x128 tile, BK=64, 4 waves (2x2), each wave 4x4 16x16x32 fragments. m97 structure.
__global__ __launch_bounds__(256) void gemm_bt_kernel(
    const ushort* __restrict__ A, const ushort* __restrict__ Bt,
    const float* __restrict__ bias1, const float* __restrict__ bias2,
    ushort* __restrict__ C, int M, int N, int K, int relu)
{
  __shared__ ushort la[128 * 64];   // 16 KB
  __shared__ ushort lb[128 * 64];   // 16 KB

  const int tid  = threadIdx.x;
  const int lane = tid & 63;
  const int w    = tid >> 6;
  const int wm   = w >> 1, wn = w & 1;
  const int ntiles = N >> 7;
  const int bm = blockIdx.x / ntiles, bn = blockIdx.x % ntiles;
  const size_t m0 = (size_t)bm << 7, n0 = (size_t)bn << 7;

  const int lrow = lane & 15;
  const int lk   = (lane >> 4) << 3;       // k offset 0/8/16/24
  const int wavebase = (tid & ~63);

  f32x4_t acc[4][4];
  const f32x4_t zero = {0.f, 0.f, 0.f, 0.f};
#pragma unroll
  for (int i = 0; i < 4; ++i)
#pragma unroll
    for (int j = 0; j < 4; ++j) acc[i][j] = zero;

  for (int k0 = 0; k0 < K; k0 += 64) {
#pragma unroll
    for (int p = 0; p < 4; ++p) {
      int c = p * 256 + tid;               // chunk 0..1023 (16B chunks)
      int r = c >> 3;                      // tile row 0..127
      int q = (c & 7) << 3;                // k element offset within row
      gl_lds16(A + (m0 + r) * (size_t)K + k0 + q, la + (size_t)(p * 256 + wavebase) * 8);
      gl_lds16(Bt + (n0 + r) * (size_t)K + k0 + q, lb + (size_t)(p * 256 + wavebase) * 8);
    }
    __syncthreads();
#pragma unroll
    for (int kk = 0; kk < 64; kk += 32) {
      bf16x8_t af[4], bfr[4];
#pragma unroll
      for (int i = 0; i < 4; ++i)
        af[i] = *(const bf16x8_t*)(la + (wm * 64 + i * 16 + lrow) * 64 + kk + lk);
#pragma unroll
      for (int j = 0; j < 4; ++j)
        bfr[j] = *(const bf16x8_t*)(lb + (wn * 64 + j * 16 + lrow) * 64 + kk + lk);
#pragma unroll
      for (int i = 0; i < 4; ++i)
#pragma unroll
        for (int j = 0; j < 4; ++j)
          acc[i][j] = mfma16(af[i], bfr[j], acc[i][j]);
    }
    __syncthreads();
  }

  const int crow0 = (lane >> 4) * 4;
#pragma unroll
  for (int j = 0; j < 4; ++j) {
    int col = (int)n0 + wn * 64 + j * 16 + lrow;
    float bv = bias1 ? bias1[col] : 0.f;
    if (bias2) bv += bias2[col];
#pragma unroll
    for (int i = 0; i < 4; ++i) {
#pragma unroll
      for (int r = 0; r < 4; ++r) {
        size_t row = m0 + wm * 64 + i * 16 + crow0 + r;
        float v = acc[i][j][r] + bv;
        if (relu) v = fmaxf(v, 0.f);
        C[row * (size_t)N + col] = f2bf(v);
      }
    }
  }
}

// ---------------- persistent LSTM scan (chunk [t0, t0+nsteps)) ----------------
// Grid: 128 WGs = 2 batch halves x 64 j-slices (16 hidden each).
// W_hh slice LDS-resident across the chunk; c persisted in cbuf (f32) across chunks;
// h double-buffered in global hbuf with parity t0&1.
__global__ __launch_bounds__(256, 1) void lstm_scan_kernel(
    const ushort* __restrict__ xg,      // (nsteps,B,4H) bf16 chunk
    const ushort* __restrict__ whh,     // (4H,H) bf16
    const int* __restrict__ mask,       // (nsteps,B) chunk (pre-offset)
    ushort* __restrict__ hbuf,          // (2,B,H) bf16 (zeroed at launch start)
    ushort* __restrict__ latent,        // (nsteps,B,H) bf16 chunk
    float* __restrict__ cbuf,           // (B,H) f32 persistent cell state
    float* __restrict__ outh, float* __restrict__ outc,   // (B,H) f32
    unsigned* __restrict__ bar,         // zeroed before each chunk
    int t0, int nsteps)
{
  __shared__ ushort lwh[WHROWS * WHPAD];   // 132 KB
  __shared__ float  lg[64 * 68];           // 17 KB (padded stride 68)

  const int tid  = threadIdx.x;
  const int lane = tid & 63;
  const int w    = tid >> 6;
  const int bg   = blockIdx.x >> 6;        // batch half
  const int jg   = blockIdx.x & 63;        // j slice
  const int j0   = jg * JG;
  const int b0   = bg * 64;

  // Load W_hh slice: LDS row r = g*16 + jj  <-  global row g*HID + j0 + jj
  for (int c = tid; c < WHROWS * (HID / 8); c += 256) {
    int r = c >> 7;
    int q = (c & 127) << 3;
    int g = r >> 4, jj = r & 15;
    const ushort* src = whh + (size_t)(g * HID + j0 + jj) * HID + q;
    *reinterpret_cast<uint4*>(&lwh[r * WHPAD + q]) = *reinterpret_cast<const uint4*>(src);
  }
  __syncthreads();

  const int lrow = lane & 15;
  const int lkg  = lane >> 4;
  const int wm = w >> 1, wn = w & 1;       // wave tile: rows wm*32, cols wn*32

  const int eb    = tid >> 2;              // epilogue batch 0..63
  const int ejq   = tid & 3;               // j quarter
  const int bge   = b0 + eb;               // global batch index

  float creg[4];
  if (t0 == 0) {
    creg[0] = creg[1] = creg[2] = creg[3] = 0.f;
  } else {
#pragma unroll
    for (int i = 0; i < 4; ++i)
      creg[i] = cbuf[(size_t)bge * HID + j0 + ejq * 4 + i];
  }

  const f32x4_t zero = {0.f, 0.f, 0.f, 0.f};
  int cur = t0 & 1;

  for (int tl = 0; tl < nsteps; ++tl) {
    // prefetch x-gates + mask for epilogue
    const ushort* xgp = xg + ((size_t)tl * BATCH + bge) * GH + j0 + ejq * 4;
    ushort4 xgv[4];
#pragma unroll
    for (int g = 0; g < 4; ++g) xgv[g] = *(const ushort4*)(xgp + g * HID);
    const float mval = (float)mask[tl * BATCH + bge];

    // GEMM: gates[64][64] = h[b0:b0+64][:] @ whh_slice^T
    f32x4_t acc[2][2];
    acc[0][0] = zero; acc[0][1] = zero; acc[1][0] = zero; acc[1][1] = zero;
    const ushort* hsrc = hbuf + (size_t)cur * (BATCH * HID);
#pragma unroll 4
    for (int ks = 0; ks < HID / 32; ++ks) {
      int k0 = ks * 32 + lkg * 8;
      bf16x8_t a0  = *(const bf16x8_t*)(hsrc + (size_t)(b0 + wm * 32 + lrow) * HID + k0);
      bf16x8_t a1  = *(const bf16x8_t*)(hsrc + (size_t)(b0 + wm * 32 + 16 + lrow) * HID + k0);
      bf16x8_t bb0 = *(const bf16x8_t*)(lwh + (wn * 32 + lrow) * WHPAD + k0);
      bf16x8_t bb1 = *(const bf16x8_t*)(lwh + (wn * 32 + 16 + lrow) * WHPAD + k0);
      acc[0][0] = mfma16(a0, bb0, acc[0][0]);
      acc[0][1] = mfma16(a0, bb1, acc[0][1]);
      acc[1][0] = mfma16(a1, bb0, acc[1][0]);
      acc[1][1] = mfma16(a1, bb1, acc[1][1]);
    }
    // scatter accumulators to LDS gate buffer
#pragma unroll
    for (int i = 0; i < 2; ++i)
#pragma unroll
      for (int j = 0; j < 2; ++j)
#pragma unroll
        for (int r = 0; r < 4; ++r)
          lg[(wm * 32 + i * 16 + lkg * 4 + r) * 68 + wn * 32 + j * 16 + lrow] = acc[i][j][r];
    __syncthreads();

    // epilogue: nonlinearities + state update (thread owns (b, 4 j's))
    float pre[4][4];
#pragma unroll
    for (int g = 0; g < 4; ++g) {
      const float* lp = &lg[eb * 68 + g * 16 + ejq * 4];
      pre[g][0] = lp[0] + bf2f(xgv[g].x);
      pre[g][1] = lp[1] + bf2f(xgv[g].y);
      pre[g][2] = lp[2] + bf2f(xgv[g].z);
      pre[g][3] = lp[3] + bf2f(xgv[g].w);
    }
    float hnv[4];
#pragma unroll
    for (int i = 0; i < 4; ++i) {
      float ig = sigm(pre[0][i]);
      float fg = sigm(pre[1][i]);
      float gg = tanhf(pre[2][i]);
      float og = sigm(pre[3][i]);
      float cpre = fg * creg[i] + ig * gg;
      float cn = cpre * mval;
      float hn = og * tanhf(cpre) * mval;
      creg[i] = cn;
      hnv[i] = hn;
    }
    ushort4 hb;
    hb.x = f2bf(hnv[0]); hb.y = f2bf(hnv[1]); hb.z = f2bf(hnv[2]); hb.w = f2bf(hnv[3]);
    *(ushort4*)(hbuf + (size_t)(cur ^ 1) * (BATCH * HID) + (size_t)bge * HID + j0 + ejq * 4) = hb;
    *(ushort4*)(latent + ((size_t)tl * BATCH + bge) * HID + j0 + ejq * 4) = hb;
    if (t0 + tl == T_STEPS - 1) {
#pragma unroll
      for (int i = 0; i < 4; ++i) {
        outh[(size_t)bge * HID + j0 + ejq * 4 + i] = hnv[i];
        outc[(size_t)bge * HID + j0 + ejq * 4 + i] = creg[i];
      }
    }

    // grid barrier (skip after last local step; kernel boundary syncs chunks)
    __syncthreads();
    if (tl != nsteps - 1) {
      if (tid == 0) {
        __threadfence();
        __hip_atomic_fetch_add(bar, 1u, __ATOMIC_RELEASE, __HIP_MEMORY_SCOPE_AGENT);
        unsigned tgt = (unsigned)(tl + 1) * (unsigned)NWG;
        while (__hip_atomic_load(bar, __ATOMIC_RELAXED, __HIP_MEMORY_SCOPE_AGENT) < tgt) {}
        (void)__hip_atomic_load(bar, __ATOMIC_ACQUIRE, __HIP_MEMORY_SCOPE_AGENT);
      }
      __syncthreads();
    }
    cur ^= 1;
  }

  // persist cell state for next chunk
#pragma unroll
  for (int i = 0; i < 4; ++i)
    cbuf[(size_t)bge * HID + j0 + ejq * 4 + i] = creg[i];
}

// ---------------- decode extract: values = bf16(Cpad[:, :18]) * mask ----------------
__global__ void extract_kernel(const ushort* __restrict__ cpad, const int* __restrict__ mask,
                               float* __restrict__ values) {
  int row = blockIdx.x * blockDim.x + threadIdx.x;   // 0..rows-1 (chunk)
  float m = (float)mask[row];
  const ushort* cr = cpad + (size_t)row * 128;
  float* vr = values + (size_t)row * ACTD;
#pragma unroll
  for (int a = 0; a < ACTD; ++a) vr[a] = bf2f(cr[a]) * m;
}

extern "C" void kernel_launch(void* const* d_in, const int* in_sizes, int n_in,
                              void* d_out, int out_size, void* d_ws, size_t ws_size,
                              hipStream_t stream) {
  (void)in_sizes; (void)n_in; (void)out_size;
  const float* state = (const float*)d_in[0];
  const int*   mask  = (const int*)d_in[1];
  const float* Wenc  = (const float*)d_in[2];
  const float* benc  = (const float*)d_in[3];
  const float* Wih   = (const float*)d_in[4];
  const float* Whh   = (const float*)d_in[5];
  const float* bih   = (const float*)d_in[6];
  const float* bhh   = (const float*)d_in[7];
  const float* Wdec  = (const float*)d_in[8];
  const float* bdec  = (const float*)d_in[9];

  float* out_values = (float*)d_out;                       // T*B*A
  float* out_h = out_values + (size_t)TBROWS * ACTD;       // B*H
  float* out_c = out_h + (size_t)BATCH * HID;              // B*H

  auto pad256 = [](size_t b) { return (b + 255) & ~(size_t)255; };

  // fixed allocations
  const size_t sz_wenc = (size_t)HID * OBSD * 2;
  const size_t sz_wih  = (size_t)GH * HID * 2;
  const size_t sz_whh  = (size_t)GH * HID * 2;
  const size_t sz_wdec = (size_t)128 * HID * 2;
  const size_t sz_bdec = 512;
  const size_t sz_bar  = 256;
  const size_t sz_hbuf = (size_t)2 * BATCH * HID * 2;
  const size_t sz_cbuf = (size_t)BATCH * HID * 4;
  const size_t fixed = pad256(sz_wenc) + pad256(sz_wih) + pad256(sz_whh) +
                       pad256(sz_wdec) + pad256(sz_bdec) + pad256(sz_bar) +
                       pad256(sz_hbuf) + pad256(sz_cbuf);

  // pick largest chunk size Tc whose footprint fits ws_size
  int Tc = 8;
  {
    const int cands[6] = {256, 128, 64, 32, 16, 8};
    for (int ci = 0; ci < 6; ++ci) {
      int tc = cands[ci];
      size_t per = pad256((size_t)tc * BATCH * OBSD * 2)      // state chunk
                 + pad256((size_t)tc * BATCH * HID * 2)       // enc chunk
                 + pad256((size_t)tc * BATCH * GH * 2)        // xg chunk
                 + pad256((size_t)tc * BATCH * HID * 2)       // lat chunk
                 + pad256((size_t)tc * BATCH * 128 * 2);      // cpad chunk
      if (fixed + per <= ws_size) { Tc = tc; break; }
    }
  }
  const int nchunks = T_STEPS / Tc;
  const int crows = Tc * BATCH;

  char* ws = (char*)d_ws;
  size_t off = 0;
  auto alloc = [&](size_t b) { char* r = ws + off; off += pad256(b); return r; };
  ushort* wenc_bf  = (ushort*)alloc(sz_wenc);
  ushort* wih_bf   = (ushort*)alloc(sz_wih);
  ushort* whh_bf   = (ushort*)alloc(sz_whh);
  ushort* wdec_pad = (ushort*)alloc(sz_wdec);
  float*  bdec_pad = (float*)alloc(sz_bdec);
  unsigned* bar    = (unsigned*)alloc(sz_bar);
  ushort* hbuf     = (ushort*)alloc(sz_hbuf);
  float*  cbuf     = (float*)alloc(sz_cbuf);
  ushort* state_c  = (ushort*)alloc((size_t)crows * OBSD * 2);
  ushort* enc_c    = (ushort*)alloc((size_t)crows * HID * 2);
  ushort* xg_c     = (ushort*)alloc((size_t)crows * GH * 2);
  ushort* lat_c    = (ushort*)alloc((size_t)crows * HID * 2);
  ushort* cpad_c   = (ushort*)alloc((size_t)crows * 128 * 2);

  hipMemsetAsync(hbuf, 0, sz_hbuf, stream);
  hipMemsetAsync(wdec_pad, 0, sz_wdec, stream);
  hipMemsetAsync(bdec_pad, 0, sz_bdec, stream);
  hipMemcpyAsync(bdec_pad, bdec, ACTD * sizeof(float), hipMemcpyDeviceToDevice, stream);

  auto cast = [&](const float* src, ushort* dst, size_t n) {
    int n4 = (int)(n / 4);
    int blocks = (n4 + 255) / 256;
    if (blocks > 4096) blocks = 4096;
    cast_bf16_kernel<<<blocks, 256, 0, stream>>>(src, dst, n4);
  };
  cast(Wenc, wenc_bf, (size_t)HID * OBSD);
  cast(Wih, wih_bf, (size_t)GH * HID);
  cast(Whh, whh_bf, (size_t)GH * HID);
  cast(Wdec, wdec_pad, (size_t)ACTD * HID);   // first 18 rows of padded buffer

  for (int c = 0; c < nchunks; ++c) {
    const int t0 = c * Tc;
    // cast state chunk
    cast(state + (size_t)t0 * BATCH * OBSD, state_c, (size_t)crows * OBSD);
    // encode: relu(state @ Wenc^T + b_enc)
    gemm_bt_kernel<<<(crows / 128) * (HID / 128), 256, 0, stream>>>(
        state_c, wenc_bf, benc, nullptr, enc_c, crows, HID, OBSD, 1);
    // x-gates: enc @ Wih^T + b_ih + b_hh
    gemm_bt_kernel<<<(crows / 128) * (GH / 128), 256, 0, stream>>>(
        enc_c, wih_bf, bih, bhh, xg_c, crows, GH, HID, 0);
    // sequential scan over this chunk
    hipMemsetAsync(bar, 0, 4, stream);
    lstm_scan_kernel<<<NWG, 256, 0, stream>>>(
        xg_c, whh_bf, mask + (size_t)t0 * BATCH, hbuf, lat_c, cbuf,
        out_h, out_c, bar, t0, Tc);
    // decode: lat @ Wdec_pad^T + b_dec_pad  (N padded to 128)
    gemm_bt_kernel<<<crows / 128, 256, 0, stream>>>(
        lat_c, wdec_pad, bdec_pad, nullptr, cpad_c, crows, 128, HID, 0);
    extract_kernel<<<crows / 256, 256, 0, stream>>>(
        cpad_c, mask + (size_t)t0 * BATCH, out_values + (size_t)t0 * BATCH * ACTD);
  }
}

// Round 3
// 5891.333 us; speedup vs baseline: 1.1193x; 1.1193x over previous
//
#include <hip/hip_runtime.h>

#define T_STEPS 256
#define BATCH   128
#define OBSD    512
#define HID     1024
#define GH      4096
#define ACTD    18
#define TBROWS  (T_STEPS*BATCH)   // 32768
#define NWG     128               // scan workgroups (2 batch halves x 64 j-slices)
#define JG      16                // hidden units per scan WG
#define WHROWS  64                // 4 gates * JG
#define WHPAD   1032              // 1024 + 8 (bank-conflict pad)

typedef __bf16 bf16x8_t __attribute__((ext_vector_type(8)));
typedef float  f32x4_t  __attribute__((ext_vector_type(4)));

__device__ __forceinline__ ushort f2bf(float f) {
  unsigned u = __builtin_bit_cast(unsigned, f);
  u += 0x7fffu + ((u >> 16) & 1u);          // RNE
  return (ushort)(u >> 16);
}
__device__ __forceinline__ float bf2f(ushort s) {
  return __builtin_bit_cast(float, ((unsigned)s) << 16);
}
__device__ __forceinline__ f32x4_t mfma16(bf16x8_t a, bf16x8_t b, f32x4_t c) {
  return __builtin_amdgcn_mfma_f32_16x16x32_bf16(a, b, c, 0, 0, 0);
}
__device__ __forceinline__ void gl_lds16(const void* g, void* l) {
  __builtin_amdgcn_global_load_lds(
      (__attribute__((address_space(1))) void*)(g),
      (__attribute__((address_space(3))) void*)(l), 16, 0, 0);
}
__device__ __forceinline__ float sigm(float x) { return 1.f / (1.f + __expf(-x)); }

// ---------------- cast f32 -> bf16 ----------------
__global__ void cast_bf16_kernel(const float* __restrict__ in, ushort* __restrict__ out, int n4) {
  int i = blockIdx.x * blockDim.x + threadIdx.x;
  int stride = gridDim.x * blockDim.x;
  for (; i < n4; i += stride) {
    float4 v = reinterpret_cast<const float4*>(in)[i];
    ushort4 o;
    o.x = f2bf(v.x); o.y = f2bf(v.y); o.z = f2bf(v.z); o.w = f2bf(v.w);
    reinterpret_cast<ushort4*>(out)[i] = o;
  }
}

// ---------------- bf16 GEMM: C = act(A @ Bt^T + bias1 [+ bias2]) ----------------
// A: (M,K) bf16 row-major; Bt: (N,K) bf16 row-major; C: (M,N) bf16.
// 128x128 tile, BK=64, 4 waves (2x2), m97 structure. XCD-swizzled blockIdx.
// If ovals != nullptr: instead of writing bf16 C, write f32 ovals[row*ACTD+col]
// = (acc+bias)*mask for col < ACTD (fused decode+mask+extract; requires single
// N-tile, i.e. N==128).
__global__ __launch_bounds__(256) void gemm_bt_kernel(
    const ushort* __restrict__ A, const ushort* __restrict__ Bt,
    const float* __restrict__ bias1, const float* __restrict__ bias2,
    ushort* __restrict__ C, int M, int N, int K, int relu,
    const int* __restrict__ omask, float* __restrict__ ovals)
{
  __shared__ ushort la[128 * 64];   // 16 KB
  __shared__ ushort lb[128 * 64];   // 16 KB

  const int tid  = threadIdx.x;
  const int lane = tid & 63;
  const int w    = tid >> 6;
  const int wm   = w >> 1, wn = w & 1;
  // XCD-aware swizzle (grid is always a multiple of 8 here)
  const int nwg = gridDim.x;
  const int q8  = nwg >> 3;
  const int bid = (blockIdx.x & 7) * q8 + (blockIdx.x >> 3);
  const int ntiles = N >> 7;
  const int bm = bid / ntiles, bn = bid % ntiles;
  const size_t m0 = (size_t)bm << 7, n0 = (size_t)bn << 7;

  const int lrow = lane & 15;
  const int lk   = (lane >> 4) << 3;       // k offset 0/8/16/24
  const int wavebase = (tid & ~63);

  f32x4_t acc[4][4];
  const f32x4_t zero = {0.f, 0.f, 0.f, 0.f};
#pragma unroll
  for (int i = 0; i < 4; ++i)
#pragma unroll
    for (int j = 0; j < 4; ++j) acc[i][j] = zero;

  for (int k0 = 0; k0 < K; k0 += 64) {
#pragma unroll
    for (int p = 0; p < 4; ++p) {
      int c = p * 256 + tid;               // chunk 0..1023 (16B chunks)
      int r = c >> 3;                      // tile row 0..127
      int q = (c & 7) << 3;                // k element offset within row
      gl_lds16(A + (m0 + r) * (size_t)K + k0 + q, la + (size_t)(p * 256 + wavebase) * 8);
      gl_lds16(Bt + (n0 + r) * (size_t)K + k0 + q, lb + (size_t)(p * 256 + wavebase) * 8);
    }
    __syncthreads();
#pragma unroll
    for (int kk = 0; kk < 64; kk += 32) {
      bf16x8_t af[4], bfr[4];
#pragma unroll
      for (int i = 0; i < 4; ++i)
        af[i] = *(const bf16x8_t*)(la + (wm * 64 + i * 16 + lrow) * 64 + kk + lk);
#pragma unroll
      for (int j = 0; j < 4; ++j)
        bfr[j] = *(const bf16x8_t*)(lb + (wn * 64 + j * 16 + lrow) * 64 + kk + lk);
#pragma unroll
      for (int i = 0; i < 4; ++i)
#pragma unroll
        for (int j = 0; j < 4; ++j)
          acc[i][j] = mfma16(af[i], bfr[j], acc[i][j]);
    }
    __syncthreads();
  }

  const int crow0 = (lane >> 4) * 4;
  if (ovals) {
    // fused decode epilogue: f32 out, masked, only cols < ACTD (N single-tile)
#pragma unroll
    for (int j = 0; j < 4; ++j) {
      int col = wn * 64 + j * 16 + lrow;
      if (col < ACTD) {
        float bv = bias1[col];
#pragma unroll
        for (int i = 0; i < 4; ++i) {
#pragma unroll
          for (int r = 0; r < 4; ++r) {
            size_t row = m0 + wm * 64 + i * 16 + crow0 + r;
            float mv = (float)omask[row];
            ovals[row * ACTD + col] = (acc[i][j][r] + bv) * mv;
          }
        }
      }
    }
    return;
  }
#pragma unroll
  for (int j = 0; j < 4; ++j) {
    int col = (int)n0 + wn * 64 + j * 16 + lrow;
    float bv = bias1 ? bias1[col] : 0.f;
    if (bias2) bv += bias2[col];
#pragma unroll
    for (int i = 0; i < 4; ++i) {
#pragma unroll
      for (int r = 0; r < 4; ++r) {
        size_t row = m0 + wm * 64 + i * 16 + crow0 + r;
        float v = acc[i][j][r] + bv;
        if (relu) v = fmaxf(v, 0.f);
        C[row * (size_t)N + col] = f2bf(v);
      }
    }
  }
}

// ---------------- persistent LSTM scan (chunk [t0, t0+nsteps)) ----------------
// 128 WGs = 2 batch halves x 64 j-slices. W_hh slice LDS-resident; c in regs.
// Flag-based grid barrier (per-WG 64B-strided flags; wave0 polls all 128).
// Deep rolling register prefetch for the global h loads in the K-loop.
__global__ __launch_bounds__(256, 1) void lstm_scan_kernel(
    const ushort* __restrict__ xg,      // (nsteps,B,4H) bf16 chunk
    const ushort* __restrict__ whh,     // (4H,H) bf16
    const int* __restrict__ mask,       // (nsteps,B) chunk (pre-offset)
    ushort* __restrict__ hbuf,          // (2,B,H) bf16 (zeroed at launch start)
    ushort* __restrict__ latent,        // (nsteps,B,H) bf16 chunk
    float* __restrict__ cbuf,           // (B,H) f32 persistent cell state
    float* __restrict__ outh, float* __restrict__ outc,   // (B,H) f32
    unsigned* __restrict__ flags,       // 128 x 16 uints, zeroed once per launch
    int t0, int nsteps)
{
  __shared__ ushort lwh[WHROWS * WHPAD];   // 132 KB
  __shared__ float  lg[64 * 68];           // 17 KB (padded stride 68)

  const int tid  = threadIdx.x;
  const int lane = tid & 63;
  const int w    = tid >> 6;
  const int wg   = blockIdx.x;
  const int bg   = wg >> 6;                // batch half
  const int jg   = wg & 63;                // j slice
  const int j0   = jg * JG;
  const int b0   = bg * 64;

  // Load W_hh slice: LDS row r = g*16 + jj  <-  global row g*HID + j0 + jj
  for (int c = tid; c < WHROWS * (HID / 8); c += 256) {
    int r = c >> 7;
    int q = (c & 127) << 3;
    int g = r >> 4, jj = r & 15;
    const ushort* src = whh + (size_t)(g * HID + j0 + jj) * HID + q;
    *reinterpret_cast<uint4*>(&lwh[r * WHPAD + q]) = *reinterpret_cast<const uint4*>(src);
  }
  __syncthreads();

  const int lrow = lane & 15;
  const int lkg  = lane >> 4;
  const int wm = w >> 1, wn = w & 1;       // wave tile: rows wm*32, cols wn*32

  const int eb    = tid >> 2;              // epilogue batch 0..63
  const int ejq   = tid & 3;               // j quarter
  const int bge   = b0 + eb;               // global batch index

  float creg[4];
  if (t0 == 0) {
    creg[0] = creg[1] = creg[2] = creg[3] = 0.f;
  } else {
#pragma unroll
    for (int i = 0; i < 4; ++i)
      creg[i] = cbuf[(size_t)bge * HID + j0 + ejq * 4 + i];
  }

  const f32x4_t zero = {0.f, 0.f, 0.f, 0.f};
  int cur = t0 & 1;

  // x-gates / mask prefetch registers (refilled during the barrier spin)
  ushort4 xgv[4];
  float mval;
  {
    const ushort* xgp = xg + ((size_t)0 * BATCH + bge) * GH + j0 + ejq * 4;
#pragma unroll
    for (int g = 0; g < 4; ++g) xgv[g] = *(const ushort4*)(xgp + g * HID);
    mval = (float)mask[0 * BATCH + bge];
  }

  for (int tl = 0; tl < nsteps; ++tl) {
    // ---- GEMM: gates[64][64] = h[b0:b0+64][:] @ whh_slice^T ----
    f32x4_t acc00 = zero, acc01 = zero, acc10 = zero, acc11 = zero;
    const ushort* hsrc = hbuf + (size_t)cur * (BATCH * HID);
    const ushort* ha0 = hsrc + (size_t)(b0 + wm * 32 + lrow) * HID + lkg * 8;
    const ushort* ha1 = ha0 + 16 * HID;
    const ushort* lbb = lwh + (wn * 32 + lrow) * WHPAD + lkg * 8;

    bf16x8_t ap0[8], ap1[8];
#pragma unroll
    for (int p = 0; p < 8; ++p) {
      ap0[p] = *(const bf16x8_t*)(ha0 + p * 32);
      ap1[p] = *(const bf16x8_t*)(ha1 + p * 32);
    }
#pragma unroll
    for (int ks = 0; ks < 32; ++ks) {
      bf16x8_t a0 = ap0[ks & 7], a1 = ap1[ks & 7];
      if (ks < 24) {
        ap0[ks & 7] = *(const bf16x8_t*)(ha0 + (ks + 8) * 32);
        ap1[ks & 7] = *(const bf16x8_t*)(ha1 + (ks + 8) * 32);
      }
      bf16x8_t bb0 = *(const bf16x8_t*)(lbb + ks * 32);
      bf16x8_t bb1 = *(const bf16x8_t*)(lbb + 16 * WHPAD + ks * 32);
      acc00 = mfma16(a0, bb0, acc00);
      acc01 = mfma16(a0, bb1, acc01);
      acc10 = mfma16(a1, bb0, acc10);
      acc11 = mfma16(a1, bb1, acc11);
    }
    // scatter accumulators to LDS gate buffer
#pragma unroll
    for (int r = 0; r < 4; ++r) {
      lg[(wm * 32 +  0 + lkg * 4 + r) * 68 + wn * 32 +  0 + lrow] = acc00[r];
      lg[(wm * 32 +  0 + lkg * 4 + r) * 68 + wn * 32 + 16 + lrow] = acc01[r];
      lg[(wm * 32 + 16 + lkg * 4 + r) * 68 + wn * 32 +  0 + lrow] = acc10[r];
      lg[(wm * 32 + 16 + lkg * 4 + r) * 68 + wn * 32 + 16 + lrow] = acc11[r];
    }
    __syncthreads();

    // ---- epilogue: nonlinearities + state update (thread owns (b, 4 j's)) ----
    float pre[4][4];
#pragma unroll
    for (int g = 0; g < 4; ++g) {
      const float* lp = &lg[eb * 68 + g * 16 + ejq * 4];
      pre[g][0] = lp[0] + bf2f(xgv[g].x);
      pre[g][1] = lp[1] + bf2f(xgv[g].y);
      pre[g][2] = lp[2] + bf2f(xgv[g].z);
      pre[g][3] = lp[3] + bf2f(xgv[g].w);
    }
    float hnv[4];
#pragma unroll
    for (int i = 0; i < 4; ++i) {
      float ig = sigm(pre[0][i]);
      float fg = sigm(pre[1][i]);
      float gg = tanhf(pre[2][i]);
      float og = sigm(pre[3][i]);
      float cpre = fg * creg[i] + ig * gg;
      creg[i] = cpre * mval;
      hnv[i]  = og * tanhf(cpre) * mval;
    }
    ushort4 hb;
    hb.x = f2bf(hnv[0]); hb.y = f2bf(hnv[1]); hb.z = f2bf(hnv[2]); hb.w = f2bf(hnv[3]);
    *(ushort4*)(hbuf + (size_t)(cur ^ 1) * (BATCH * HID) + (size_t)bge * HID + j0 + ejq * 4) = hb;
    *(ushort4*)(latent + ((size_t)tl * BATCH + bge) * HID + j0 + ejq * 4) = hb;
    if (t0 + tl == T_STEPS - 1) {
#pragma unroll
      for (int i = 0; i < 4; ++i) {
        outh[(size_t)bge * HID + j0 + ejq * 4 + i] = hnv[i];
        outc[(size_t)bge * HID + j0 + ejq * 4 + i] = creg[i];
      }
    }

    // ---- flag-based grid barrier (skip after last local step) ----
    if (tl != nsteps - 1) {
      __syncthreads();                       // all h stores drained (vmcnt 0 at barrier)
      const unsigned tgt = (unsigned)(t0 + tl + 1);
      if (tid == 0) {
        __threadfence();                     // flush this XCD's L2 (covers WG's stores)
        __hip_atomic_store(&flags[(size_t)wg * 16], tgt, __ATOMIC_RELEASE, __HIP_MEMORY_SCOPE_AGENT);
      }
      // overlap: prefetch next step's x-gates + mask while waiting
      {
        const ushort* xgp = xg + ((size_t)(tl + 1) * BATCH + bge) * GH + j0 + ejq * 4;
#pragma unroll
        for (int g = 0; g < 4; ++g) xgv[g] = *(const ushort4*)(xgp + g * HID);
        mval = (float)mask[(tl + 1) * BATCH + bge];
      }
      if (tid < 64) {
        for (;;) {
          unsigned a = __hip_atomic_load(&flags[(size_t)tid * 16], __ATOMIC_RELAXED, __HIP_MEMORY_SCOPE_AGENT);
          unsigned b = __hip_atomic_load(&flags[(size_t)(tid + 64) * 16], __ATOMIC_RELAXED, __HIP_MEMORY_SCOPE_AGENT);
          if (__all(a >= tgt && b >= tgt)) break;
        }
        (void)__hip_atomic_load(&flags[0], __ATOMIC_ACQUIRE, __HIP_MEMORY_SCOPE_AGENT);  // acquire (L2 inv)
      }
      __syncthreads();
    }
    cur ^= 1;
  }

  // persist cell state for next chunk
#pragma unroll
  for (int i = 0; i < 4; ++i)
    cbuf[(size_t)bge * HID + j0 + ejq * 4 + i] = creg[i];
}

extern "C" void kernel_launch(void* const* d_in, const int* in_sizes, int n_in,
                              void* d_out, int out_size, void* d_ws, size_t ws_size,
                              hipStream_t stream) {
  (void)in_sizes; (void)n_in; (void)out_size;
  const float* state = (const float*)d_in[0];
  const int*   mask  = (const int*)d_in[1];
  const float* Wenc  = (const float*)d_in[2];
  const float* benc  = (const float*)d_in[3];
  const float* Wih   = (const float*)d_in[4];
  const float* Whh   = (const float*)d_in[5];
  const float* bih   = (const float*)d_in[6];
  const float* bhh   = (const float*)d_in[7];
  const float* Wdec  = (const float*)d_in[8];
  const float* bdec  = (const float*)d_in[9];

  float* out_values = (float*)d_out;                       // T*B*A
  float* out_h = out_values + (size_t)TBROWS * ACTD;       // B*H
  float* out_c = out_h + (size_t)BATCH * HID;              // B*H

  auto pad256 = [](size_t b) { return (b + 255) & ~(size_t)255; };

  // fixed allocations
  const size_t sz_wenc  = (size_t)HID * OBSD * 2;
  const size_t sz_wih   = (size_t)GH * HID * 2;
  const size_t sz_whh   = (size_t)GH * HID * 2;
  const size_t sz_wdec  = (size_t)128 * HID * 2;
  const size_t sz_bdec  = 512;
  const size_t sz_flags = 128 * 16 * sizeof(unsigned);     // 8 KB
  const size_t sz_hbuf  = (size_t)2 * BATCH * HID * 2;
  const size_t sz_cbuf  = (size_t)BATCH * HID * 4;
  const size_t fixed = pad256(sz_wenc) + pad256(sz_wih) + pad256(sz_whh) +
                       pad256(sz_wdec) + pad256(sz_bdec) + pad256(sz_flags) +
                       pad256(sz_hbuf) + pad256(sz_cbuf);

  // pick largest chunk size Tc whose footprint fits ws_size
  int Tc = 8;
  {
    const int cands[6] = {256, 128, 64, 32, 16, 8};
    for (int ci = 0; ci < 6; ++ci) {
      int tc = cands[ci];
      size_t per = pad256((size_t)tc * BATCH * OBSD * 2)      // state chunk
                 + pad256((size_t)tc * BATCH * HID * 2)       // enc chunk
                 + pad256((size_t)tc * BATCH * GH * 2)        // xg chunk
                 + pad256((size_t)tc * BATCH * HID * 2);      // lat chunk
      if (fixed + per <= ws_size) { Tc = tc; break; }
    }
  }
  const int nchunks = T_STEPS / Tc;
  const int crows = Tc * BATCH;

  char* ws = (char*)d_ws;
  size_t off = 0;
  auto alloc = [&](size_t b) { char* r = ws + off; off += pad256(b); return r; };
  ushort* wenc_bf  = (ushort*)alloc(sz_wenc);
  ushort* wih_bf   = (ushort*)alloc(sz_wih);
  ushort* whh_bf   = (ushort*)alloc(sz_whh);
  ushort* wdec_pad = (ushort*)alloc(sz_wdec);
  float*  bdec_pad = (float*)alloc(sz_bdec);
  unsigned* flags  = (unsigned*)alloc(sz_flags);
  ushort* hbuf     = (ushort*)alloc(sz_hbuf);
  float*  cbuf     = (float*)alloc(sz_cbuf);
  ushort* state_c  = (ushort*)alloc((size_t)crows * OBSD * 2);
  ushort* enc_c    = (ushort*)alloc((size_t)crows * HID * 2);
  ushort* xg_c     = (ushort*)alloc((size_t)crows * GH * 2);
  ushort* lat_c    = (ushort*)alloc((size_t)crows * HID * 2);

  hipMemsetAsync(hbuf, 0, sz_hbuf, stream);
  hipMemsetAsync(flags, 0, sz_flags, stream);
  hipMemsetAsync(wdec_pad, 0, sz_wdec, stream);
  hipMemsetAsync(bdec_pad, 0, sz_bdec, stream);
  hipMemcpyAsync(bdec_pad, bdec, ACTD * sizeof(float), hipMemcpyDeviceToDevice, stream);

  auto cast = [&](const float* src, ushort* dst, size_t n) {
    int n4 = (int)(n / 4);
    int blocks = (n4 + 255) / 256;
    if (blocks > 4096) blocks = 4096;
    cast_bf16_kernel<<<blocks, 256, 0, stream>>>(src, dst, n4);
  };
  cast(Wenc, wenc_bf, (size_t)HID * OBSD);
  cast(Wih, wih_bf, (size_t)GH * HID);
  cast(Whh, whh_bf, (size_t)GH * HID);
  cast(Wdec, wdec_pad, (size_t)ACTD * HID);   // first 18 rows of padded buffer

  for (int c = 0; c < nchunks; ++c) {
    const int t0 = c * Tc;
    // cast state chunk
    cast(state + (size_t)t0 * BATCH * OBSD, state_c, (size_t)crows * OBSD);
    // encode: relu(state @ Wenc^T + b_enc)
    gemm_bt_kernel<<<(crows / 128) * (HID / 128), 256, 0, stream>>>(
        state_c, wenc_bf, benc, nullptr, enc_c, crows, HID, OBSD, 1, nullptr, nullptr);
    // x-gates: enc @ Wih^T + b_ih + b_hh
    gemm_bt_kernel<<<(crows / 128) * (GH / 128), 256, 0, stream>>>(
        enc_c, wih_bf, bih, bhh, xg_c, crows, GH, HID, 0, nullptr, nullptr);
    // sequential scan over this chunk (flags continue monotonically across chunks)
    lstm_scan_kernel<<<NWG, 256, 0, stream>>>(
        xg_c, whh_bf, mask + (size_t)t0 * BATCH, hbuf, lat_c, cbuf,
        out_h, out_c, flags, t0, Tc);
    // fused decode + mask + extract: values = (lat @ Wdec_pad^T + b_dec) * mask
    gemm_bt_kernel<<<crows / 128, 256, 0, stream>>>(
        lat_c, wdec_pad, bdec_pad, nullptr, nullptr, crows, 128, HID, 0,
        mask + (size_t)t0 * BATCH, out_values + (size_t)t0 * BATCH * ACTD);
  }
}

// Round 4
// 5669.260 us; speedup vs baseline: 1.1631x; 1.0392x over previous
//
#include <hip/hip_runtime.h>

#define T_STEPS 256
#define BATCH   128
#define OBSD    512
#define HID     1024
#define GH      4096
#define ACTD    18
#define TBROWS  (T_STEPS*BATCH)   // 32768
#define NWG     256               // scan WGs: 4 batch quarters x 64 j-slices
#define JG      16                // hidden units per scan WG

typedef __bf16 bf16x8_t __attribute__((ext_vector_type(8)));
typedef float  f32x4_t  __attribute__((ext_vector_type(4)));

__device__ __forceinline__ ushort f2bf(float f) {
  unsigned u = __builtin_bit_cast(unsigned, f);
  u += 0x7fffu + ((u >> 16) & 1u);          // RNE
  return (ushort)(u >> 16);
}
__device__ __forceinline__ float bf2f(ushort s) {
  return __builtin_bit_cast(float, ((unsigned)s) << 16);
}
__device__ __forceinline__ f32x4_t mfma16(bf16x8_t a, bf16x8_t b, f32x4_t c) {
  return __builtin_amdgcn_mfma_f32_16x16x32_bf16(a, b, c, 0, 0, 0);
}
__device__ __forceinline__ void gl_lds16(const void* g, void* l) {
  __builtin_amdgcn_global_load_lds(
      (__attribute__((address_space(1))) void*)(g),
      (__attribute__((address_space(3))) void*)(l), 16, 0, 0);
}
__device__ __forceinline__ float sigm(float x) { return 1.f / (1.f + __expf(-x)); }
__device__ __forceinline__ float tanhf_fast(float x) {
  float e = __expf(2.f * x);
  return (e - 1.f) / (e + 1.f);
}
// vmcnt-only waits (lgkm=15/exp=7 fields = no-wait)
__device__ __forceinline__ void wait_vm0() { __builtin_amdgcn_s_waitcnt(0x0F70); }
__device__ __forceinline__ void wait_vm2() { __builtin_amdgcn_s_waitcnt(0x0F72); }

// ---------------- cast f32 -> bf16 ----------------
__global__ void cast_bf16_kernel(const float* __restrict__ in, ushort* __restrict__ out, int n4) {
  int i = blockIdx.x * blockDim.x + threadIdx.x;
  int stride = gridDim.x * blockDim.x;
  for (; i < n4; i += stride) {
    float4 v = reinterpret_cast<const float4*>(in)[i];
    ushort4 o;
    o.x = f2bf(v.x); o.y = f2bf(v.y); o.z = f2bf(v.z); o.w = f2bf(v.w);
    reinterpret_cast<ushort4*>(out)[i] = o;
  }
}

// ---------------- cast+permute W_ih: dst row hid*4+g <- src row g*HID+hid ----------------
__global__ void cast_permute_wih_kernel(const float* __restrict__ in, ushort* __restrict__ out) {
  int idx = blockIdx.x * 256 + threadIdx.x;     // over 4096 * 128
  int rowd = idx >> 7;
  int c8 = (idx & 127) << 3;
  int g = rowd & 3, hid = rowd >> 2;
  const float* src = in + ((size_t)g * HID + hid) * HID + c8;
  ushort* dst = out + (size_t)rowd * HID + c8;
#pragma unroll
  for (int i = 0; i < 8; ++i) dst[i] = f2bf(src[i]);
}

// ---------------- bias permute: out[hid*4+g] = bih[g*H+hid] + bhh[g*H+hid] ----------------
__global__ void bias_perm_kernel(const float* __restrict__ bih, const float* __restrict__ bhh,
                                 float* __restrict__ out) {
  int i = blockIdx.x * 256 + threadIdx.x;       // 4096
  int g = i & 3, hid = i >> 2;
  out[i] = bih[g * HID + hid] + bhh[g * HID + hid];
}

// ---------------- bf16 GEMM: C = act(A @ Bt^T + bias1 [+ bias2]) ----------------
// 128x128 tile, BK=64, 4 waves (2x2), m97 structure. XCD-swizzled blockIdx.
// If ovals != nullptr: fused decode epilogue (f32, masked, cols < ACTD; N==128).
__global__ __launch_bounds__(256) void gemm_bt_kernel(
    const ushort* __restrict__ A, const ushort* __restrict__ Bt,
    const float* __restrict__ bias1, const float* __restrict__ bias2,
    ushort* __restrict__ C, int M, int N, int K, int relu,
    const int* __restrict__ omask, float* __restrict__ ovals)
{
  __shared__ ushort la[128 * 64];   // 16 KB
  __shared__ ushort lb[128 * 64];   // 16 KB

  const int tid  = threadIdx.x;
  const int lane = tid & 63;
  const int w    = tid >> 6;
  const int wm   = w >> 1, wn = w & 1;
  const int nwg = gridDim.x;
  const int q8  = nwg >> 3;
  const int bid = (blockIdx.x & 7) * q8 + (blockIdx.x >> 3);
  const int ntiles = N >> 7;
  const int bm = bid / ntiles, bn = bid % ntiles;
  const size_t m0 = (size_t)bm << 7, n0 = (size_t)bn << 7;

  const int lrow = lane & 15;
  const int lk   = (lane >> 4) << 3;
  const int wavebase = (tid & ~63);

  f32x4_t acc[4][4];
  const f32x4_t zero = {0.f, 0.f, 0.f, 0.f};
#pragma unroll
  for (int i = 0; i < 4; ++i)
#pragma unroll
    for (int j = 0; j < 4; ++j) acc[i][j] = zero;

  for (int k0 = 0; k0 < K; k0 += 64) {
#pragma unroll
    for (int p = 0; p < 4; ++p) {
      int c = p * 256 + tid;
      int r = c >> 3;
      int q = (c & 7) << 3;
      gl_lds16(A + (m0 + r) * (size_t)K + k0 + q, la + (size_t)(p * 256 + wavebase) * 8);
      gl_lds16(Bt + (n0 + r) * (size_t)K + k0 + q, lb + (size_t)(p * 256 + wavebase) * 8);
    }
    __syncthreads();
#pragma unroll
    for (int kk = 0; kk < 64; kk += 32) {
      bf16x8_t af[4], bfr[4];
#pragma unroll
      for (int i = 0; i < 4; ++i)
        af[i] = *(const bf16x8_t*)(la + (wm * 64 + i * 16 + lrow) * 64 + kk + lk);
#pragma unroll
      for (int j = 0; j < 4; ++j)
        bfr[j] = *(const bf16x8_t*)(lb + (wn * 64 + j * 16 + lrow) * 64 + kk + lk);
#pragma unroll
      for (int i = 0; i < 4; ++i)
#pragma unroll
        for (int j = 0; j < 4; ++j)
          acc[i][j] = mfma16(af[i], bfr[j], acc[i][j]);
    }
    __syncthreads();
  }

  const int crow0 = (lane >> 4) * 4;
  if (ovals) {
#pragma unroll
    for (int j = 0; j < 4; ++j) {
      int col = wn * 64 + j * 16 + lrow;
      if (col < ACTD) {
        float bv = bias1[col];
#pragma unroll
        for (int i = 0; i < 4; ++i) {
#pragma unroll
          for (int r = 0; r < 4; ++r) {
            size_t row = m0 + wm * 64 + i * 16 + crow0 + r;
            float mv = (float)omask[row];
            ovals[row * ACTD + col] = (acc[i][j][r] + bv) * mv;
          }
        }
      }
    }
    return;
  }
#pragma unroll
  for (int j = 0; j < 4; ++j) {
    int col = (int)n0 + wn * 64 + j * 16 + lrow;
    float bv = bias1 ? bias1[col] : 0.f;
    if (bias2) bv += bias2[col];
#pragma unroll
    for (int i = 0; i < 4; ++i) {
#pragma unroll
      for (int r = 0; r < 4; ++r) {
        size_t row = m0 + wm * 64 + i * 16 + crow0 + r;
        float v = acc[i][j][r] + bv;
        if (relu) v = fmaxf(v, 0.f);
        C[row * (size_t)N + col] = f2bf(v);
      }
    }
  }
}

// ---------------- persistent LSTM scan (chunk [t0, t0+nsteps)) ----------------
// 256 WGs = 4 batch quarters x 64 j-slices (16 hidden each).
// gates^T = W_slice @ h^T: all 4 gates of a (b,jj) cell land in one lane's f32x4.
// h staged via global_load_lds (8 chunks x 8KB, 3 buffers, counted vmcnt).
// xg is pre-permuted: xg[t][b][jj*4+g]. W_hh gathered into LDS in rr=jj*4+g order.
__global__ __launch_bounds__(256, 1) void lstm_scan_kernel(
    const ushort* __restrict__ xg,      // (nsteps,B,4H) bf16, gate-permuted
    const ushort* __restrict__ whh,     // (4H,H) bf16 natural
    const int* __restrict__ mask,       // (nsteps,B) (pre-offset)
    ushort* __restrict__ hbuf,          // (2,B,H) bf16 (zeroed at start)
    ushort* __restrict__ latent,        // (nsteps,B,H) bf16
    float* __restrict__ cbuf,           // (B,H) f32 persistent cell state
    float* __restrict__ outh, float* __restrict__ outc,   // (B,H) f32
    unsigned* __restrict__ flags,       // 256 x 16 uints, zeroed per launch
    int t0, int nsteps)
{
  __shared__ ushort lwh[64 * 1024];     // 128 KB, granule-XOR-swizzled
  __shared__ ushort hst[3 * 4096];      // 3 x 8 KB h staging

  const int tid  = threadIdx.x;
  const int lane = tid & 63;
  const int w    = tid >> 6;
  const int wg   = blockIdx.x;
  const int bq   = wg >> 6;            // batch quarter 0..3
  const int jg   = wg & 63;            // j slice
  const int j0   = jg * JG;
  const int b0   = bq * 32;

  // Gather W_hh slice, row rr = jj*4+g <- whh row g*H + j0+jj, granule-swizzled.
  for (int c = tid; c < 64 * 128; c += 256) {
    int r = c >> 7, gn = c & 127;
    int jj = r >> 2, g = r & 3;
    const ushort* src = whh + ((size_t)g * HID + j0 + jj) * HID + gn * 8;
    int gnd = (gn & ~7) | ((gn & 7) ^ (r & 7));
    *reinterpret_cast<uint4*>(&lwh[r * 1024 + gnd * 8]) =
        *reinterpret_cast<const uint4*>(src);
  }
  __syncthreads();

  const int lrow = lane & 15;
  const int lkg  = lane >> 4;

  // cell mapping: jjc = w*4+lkg; local batch rows bl0 = lrow, bl1 = 16+lrow
  const int jjc = w * 4 + lkg;
  const int bl0 = lrow, bl1 = 16 + lrow;

  float creg0, creg1;
  if (t0 == 0) { creg0 = creg1 = 0.f; }
  else {
    creg0 = cbuf[(size_t)(b0 + bl0) * HID + j0 + jjc];
    creg1 = cbuf[(size_t)(b0 + bl1) * HID + j0 + jjc];
  }

  int cur = t0 & 1;

  // staging DMA constants: slots s0 = w*128+lane (instr0), s1 = s0+64 (instr1)
  const int s0 = w * 128 + lane;
  const int s1 = s0 + 64;
  const int sb0 = s0 >> 4, sq0 = s0 & 15;
  const int sb1 = s1 >> 4, sq1 = s1 & 15;
  const int gg0 = (sq0 & 8) | ((sq0 & 7) ^ (sb0 & 7));   // source granule (swizzle inverse)
  const int gg1 = (sq1 & 8) | ((sq1 & 7) ^ (sb1 & 7));

  // prefetch xg/mask for step 0
  ushort4 xv0, xv1;
  float m0v, m1v;
  {
    xv0 = *(const ushort4*)(xg + (size_t)(b0 + bl0) * GH + (j0 + jjc) * 4);
    xv1 = *(const ushort4*)(xg + (size_t)(b0 + bl1) * GH + (j0 + jjc) * 4);
    m0v = (float)mask[b0 + bl0];
    m1v = (float)mask[b0 + bl1];
  }
  __builtin_amdgcn_sched_barrier(0);

  for (int tl = 0; tl < nsteps; ++tl) {
    const ushort* hsrc = hbuf + (size_t)cur * (BATCH * HID) + (size_t)b0 * HID;

    wait_vm0();                          // clean vmcnt slate (prefetch drained)
    __builtin_amdgcn_sched_barrier(0);

    f32x4_t acc0 = {0.f, 0.f, 0.f, 0.f};
    f32x4_t acc1 = {0.f, 0.f, 0.f, 0.f};

    // prologue: stage chunks 0,1
#pragma unroll
    for (int kc = 0; kc < 2; ++kc) {
      gl_lds16(hsrc + (size_t)sb0 * HID + (kc * 16 + gg0) * 8, hst + (size_t)kc * 4096 + (size_t)(w * 128) * 8);
      gl_lds16(hsrc + (size_t)sb1 * HID + (kc * 16 + gg1) * 8, hst + (size_t)kc * 4096 + (size_t)(w * 128 + 64) * 8);
    }
    __builtin_amdgcn_sched_barrier(0);

#pragma unroll
    for (int kc = 0; kc < 8; ++kc) {
      if (kc < 7) wait_vm2(); else wait_vm0();
      __builtin_amdgcn_s_barrier();
      __builtin_amdgcn_sched_barrier(0);
      const ushort* sbuf = hst + (size_t)(kc % 3) * 4096;
#pragma unroll
      for (int ks = 0; ks < 4; ++ks) {
        int gA = kc * 16 + ks * 4 + lkg;
        int gAs = (gA & ~7) | ((gA & 7) ^ (lrow & 7));   // (w*16+lrow)&7 == lrow&7
        bf16x8_t af = *(const bf16x8_t*)(lwh + (size_t)(w * 16 + lrow) * 1024 + gAs * 8);
        int q16 = ks * 4 + lkg;
        int qs = (q16 & 8) | ((q16 & 7) ^ (bl0 & 7));    // bl1&7 == bl0&7
        bf16x8_t bf0 = *(const bf16x8_t*)(sbuf + (size_t)bl0 * 128 + qs * 8);
        bf16x8_t bf1 = *(const bf16x8_t*)(sbuf + (size_t)bl1 * 128 + qs * 8);
        acc0 = mfma16(af, bf0, acc0);
        acc1 = mfma16(af, bf1, acc1);
      }
      if (kc < 6) {
        int kn = kc + 2;
        int p = kn % 3;
        gl_lds16(hsrc + (size_t)sb0 * HID + (kn * 16 + gg0) * 8, hst + (size_t)p * 4096 + (size_t)(w * 128) * 8);
        gl_lds16(hsrc + (size_t)sb1 * HID + (kn * 16 + gg1) * 8, hst + (size_t)p * 4096 + (size_t)(w * 128 + 64) * 8);
      }
      __builtin_amdgcn_sched_barrier(0);
    }

    // ---- epilogue: fragment-native nonlinearities (lane owns 2 cells) ----
    {
      float ig = sigm(acc0[0] + bf2f(xv0.x));
      float fg = sigm(acc0[1] + bf2f(xv0.y));
      float gt = tanhf_fast(acc0[2] + bf2f(xv0.z));
      float og = sigm(acc0[3] + bf2f(xv0.w));
      float cp = fg * creg0 + ig * gt;
      creg0 = cp * m0v;
      float h0 = og * tanhf_fast(cp) * m0v;

      ig = sigm(acc1[0] + bf2f(xv1.x));
      fg = sigm(acc1[1] + bf2f(xv1.y));
      gt = tanhf_fast(acc1[2] + bf2f(xv1.z));
      og = sigm(acc1[3] + bf2f(xv1.w));
      cp = fg * creg1 + ig * gt;
      creg1 = cp * m1v;
      float h1 = og * tanhf_fast(cp) * m1v;

      ushort hb0 = f2bf(h0), hb1 = f2bf(h1);
      ushort* hdst = hbuf + (size_t)(cur ^ 1) * (BATCH * HID);
      hdst[(size_t)(b0 + bl0) * HID + j0 + jjc] = hb0;
      hdst[(size_t)(b0 + bl1) * HID + j0 + jjc] = hb1;
      ushort* ldst = latent + (size_t)tl * BATCH * HID;
      ldst[(size_t)(b0 + bl0) * HID + j0 + jjc] = hb0;
      ldst[(size_t)(b0 + bl1) * HID + j0 + jjc] = hb1;
      if (t0 + tl == T_STEPS - 1) {
        outh[(size_t)(b0 + bl0) * HID + j0 + jjc] = h0;
        outh[(size_t)(b0 + bl1) * HID + j0 + jjc] = h1;
        outc[(size_t)(b0 + bl0) * HID + j0 + jjc] = creg0;
        outc[(size_t)(b0 + bl1) * HID + j0 + jjc] = creg1;
      }
    }

    // ---- flag-based grid barrier (skip after last local step) ----
    if (tl != nsteps - 1) {
      __syncthreads();                   // drains all waves' stores (vmcnt 0)
      const unsigned tgt = (unsigned)(t0 + tl + 1);
      if (tid == 0) {
        __threadfence();                 // L2 writeback (covers WG's stores)
        __hip_atomic_store(&flags[(size_t)wg * 16], tgt, __ATOMIC_RELEASE, __HIP_MEMORY_SCOPE_AGENT);
      }
      // overlap: prefetch next step's xg + mask while waiting
      {
        const ushort* xp = xg + (size_t)(tl + 1) * BATCH * GH;
        xv0 = *(const ushort4*)(xp + (size_t)(b0 + bl0) * GH + (j0 + jjc) * 4);
        xv1 = *(const ushort4*)(xp + (size_t)(b0 + bl1) * GH + (j0 + jjc) * 4);
        m0v = (float)mask[(tl + 1) * BATCH + b0 + bl0];
        m1v = (float)mask[(tl + 1) * BATCH + b0 + bl1];
      }
      __builtin_amdgcn_sched_barrier(0);
      if (tid < 64) {
        for (;;) {
          unsigned a = __hip_atomic_load(&flags[(size_t)tid * 16], __ATOMIC_RELAXED, __HIP_MEMORY_SCOPE_AGENT);
          unsigned b = __hip_atomic_load(&flags[(size_t)(tid + 64) * 16], __ATOMIC_RELAXED, __HIP_MEMORY_SCOPE_AGENT);
          unsigned c = __hip_atomic_load(&flags[(size_t)(tid + 128) * 16], __ATOMIC_RELAXED, __HIP_MEMORY_SCOPE_AGENT);
          unsigned d = __hip_atomic_load(&flags[(size_t)(tid + 192) * 16], __ATOMIC_RELAXED, __HIP_MEMORY_SCOPE_AGENT);
          if (__all(a >= tgt && b >= tgt && c >= tgt && d >= tgt)) break;
        }
        (void)__hip_atomic_load(&flags[0], __ATOMIC_ACQUIRE, __HIP_MEMORY_SCOPE_AGENT);
      }
      __syncthreads();
    }
    cur ^= 1;
  }

  // persist cell state for next chunk
  cbuf[(size_t)(b0 + bl0) * HID + j0 + jjc] = creg0;
  cbuf[(size_t)(b0 + bl1) * HID + j0 + jjc] = creg1;
}

extern "C" void kernel_launch(void* const* d_in, const int* in_sizes, int n_in,
                              void* d_out, int out_size, void* d_ws, size_t ws_size,
                              hipStream_t stream) {
  (void)in_sizes; (void)n_in; (void)out_size;
  const float* state = (const float*)d_in[0];
  const int*   mask  = (const int*)d_in[1];
  const float* Wenc  = (const float*)d_in[2];
  const float* benc  = (const float*)d_in[3];
  const float* Wih   = (const float*)d_in[4];
  const float* Whh   = (const float*)d_in[5];
  const float* bih   = (const float*)d_in[6];
  const float* bhh   = (const float*)d_in[7];
  const float* Wdec  = (const float*)d_in[8];
  const float* bdec  = (const float*)d_in[9];

  float* out_values = (float*)d_out;                       // T*B*A
  float* out_h = out_values + (size_t)TBROWS * ACTD;       // B*H
  float* out_c = out_h + (size_t)BATCH * HID;              // B*H

  auto pad256 = [](size_t b) { return (b + 255) & ~(size_t)255; };

  const size_t sz_wenc  = (size_t)HID * OBSD * 2;
  const size_t sz_wih   = (size_t)GH * HID * 2;
  const size_t sz_whh   = (size_t)GH * HID * 2;
  const size_t sz_wdec  = (size_t)128 * HID * 2;
  const size_t sz_bdec  = 512;
  const size_t sz_bperm = (size_t)GH * sizeof(float);
  const size_t sz_flags = NWG * 16 * sizeof(unsigned);     // 16 KB
  const size_t sz_hbuf  = (size_t)2 * BATCH * HID * 2;
  const size_t sz_cbuf  = (size_t)BATCH * HID * 4;
  const size_t fixed = pad256(sz_wenc) + pad256(sz_wih) + pad256(sz_whh) +
                       pad256(sz_wdec) + pad256(sz_bdec) + pad256(sz_bperm) +
                       pad256(sz_flags) + pad256(sz_hbuf) + pad256(sz_cbuf);

  int Tc = 8;
  {
    const int cands[6] = {256, 128, 64, 32, 16, 8};
    for (int ci = 0; ci < 6; ++ci) {
      int tc = cands[ci];
      size_t per = pad256((size_t)tc * BATCH * OBSD * 2)
                 + pad256((size_t)tc * BATCH * HID * 2)
                 + pad256((size_t)tc * BATCH * GH * 2)
                 + pad256((size_t)tc * BATCH * HID * 2);
      if (fixed + per <= ws_size) { Tc = tc; break; }
    }
  }
  const int nchunks = T_STEPS / Tc;
  const int crows = Tc * BATCH;

  char* ws = (char*)d_ws;
  size_t off = 0;
  auto alloc = [&](size_t b) { char* r = ws + off; off += pad256(b); return r; };
  ushort* wenc_bf  = (ushort*)alloc(sz_wenc);
  ushort* wih_perm = (ushort*)alloc(sz_wih);
  ushort* whh_bf   = (ushort*)alloc(sz_whh);
  ushort* wdec_pad = (ushort*)alloc(sz_wdec);
  float*  bdec_pad = (float*)alloc(sz_bdec);
  float*  bperm    = (float*)alloc(sz_bperm);
  unsigned* flags  = (unsigned*)alloc(sz_flags);
  ushort* hbuf     = (ushort*)alloc(sz_hbuf);
  float*  cbuf     = (float*)alloc(sz_cbuf);
  ushort* state_c  = (ushort*)alloc((size_t)crows * OBSD * 2);
  ushort* enc_c    = (ushort*)alloc((size_t)crows * HID * 2);
  ushort* xg_c     = (ushort*)alloc((size_t)crows * GH * 2);
  ushort* lat_c    = (ushort*)alloc((size_t)crows * HID * 2);

  hipMemsetAsync(hbuf, 0, sz_hbuf, stream);
  hipMemsetAsync(flags, 0, sz_flags, stream);
  hipMemsetAsync(wdec_pad, 0, sz_wdec, stream);
  hipMemsetAsync(bdec_pad, 0, sz_bdec, stream);
  hipMemcpyAsync(bdec_pad, bdec, ACTD * sizeof(float), hipMemcpyDeviceToDevice, stream);

  auto cast = [&](const float* src, ushort* dst, size_t n) {
    int n4 = (int)(n / 4);
    int blocks = (n4 + 255) / 256;
    if (blocks > 4096) blocks = 4096;
    cast_bf16_kernel<<<blocks, 256, 0, stream>>>(src, dst, n4);
  };
  cast(Wenc, wenc_bf, (size_t)HID * OBSD);
  cast(Whh, whh_bf, (size_t)GH * HID);
  cast(Wdec, wdec_pad, (size_t)ACTD * HID);
  cast_permute_wih_kernel<<<(GH * 128) / 256, 256, 0, stream>>>(Wih, wih_perm);
  bias_perm_kernel<<<GH / 256, 256, 0, stream>>>(bih, bhh, bperm);

  for (int c = 0; c < nchunks; ++c) {
    const int t0 = c * Tc;
    cast(state + (size_t)t0 * BATCH * OBSD, state_c, (size_t)crows * OBSD);
    // encode: relu(state @ Wenc^T + b_enc)
    gemm_bt_kernel<<<(crows / 128) * (HID / 128), 256, 0, stream>>>(
        state_c, wenc_bf, benc, nullptr, enc_c, crows, HID, OBSD, 1, nullptr, nullptr);
    // x-gates (gate-permuted cols): enc @ Wih_perm^T + bperm
    gemm_bt_kernel<<<(crows / 128) * (GH / 128), 256, 0, stream>>>(
        enc_c, wih_perm, bperm, nullptr, xg_c, crows, GH, HID, 0, nullptr, nullptr);
    // sequential scan over this chunk
    lstm_scan_kernel<<<NWG, 256, 0, stream>>>(
        xg_c, whh_bf, mask + (size_t)t0 * BATCH, hbuf, lat_c, cbuf,
        out_h, out_c, flags, t0, Tc);
    // fused decode + mask + extract
    gemm_bt_kernel<<<crows / 128, 256, 0, stream>>>(
        lat_c, wdec_pad, bdec_pad, nullptr, nullptr, crows, 128, HID, 0,
        mask + (size_t)t0 * BATCH, out_values + (size_t)t0 * BATCH * ACTD);
  }
}

// Round 5
// 2574.603 us; speedup vs baseline: 2.5612x; 2.2020x over previous
//
#include <hip/hip_runtime.h>

#define T_STEPS 256
#define BATCH   128
#define OBSD    512
#define HID     1024
#define GH      4096
#define ACTD    18
#define TBROWS  (T_STEPS*BATCH)   // 32768
#define NWG     256               // scan WGs: 4 batch quarters x 64 j-slices
#define JG      16                // hidden units per scan WG

typedef __bf16 bf16x8_t __attribute__((ext_vector_type(8)));
typedef float  f32x4_t  __attribute__((ext_vector_type(4)));

__device__ __forceinline__ ushort f2bf(float f) {
  unsigned u = __builtin_bit_cast(unsigned, f);
  u += 0x7fffu + ((u >> 16) & 1u);          // RNE
  return (ushort)(u >> 16);
}
__device__ __forceinline__ float bf2f(ushort s) {
  return __builtin_bit_cast(float, ((unsigned)s) << 16);
}
__device__ __forceinline__ f32x4_t mfma16(bf16x8_t a, bf16x8_t b, f32x4_t c) {
  return __builtin_amdgcn_mfma_f32_16x16x32_bf16(a, b, c, 0, 0, 0);
}
__device__ __forceinline__ void gl_lds16(const void* g, void* l) {
  __builtin_amdgcn_global_load_lds(
      (__attribute__((address_space(1))) void*)(g),
      (__attribute__((address_space(3))) void*)(l), 16, 0, 0);
}
__device__ __forceinline__ float sigm(float x) { return 1.f / (1.f + __expf(-x)); }
__device__ __forceinline__ float tanhf_fast(float x) {
  float e = __expf(2.f * x);
  return (e - 1.f) / (e + 1.f);
}
// vmcnt-only waits (lgkm=15/exp=7 fields = no-wait)
__device__ __forceinline__ void wait_vm0() { __builtin_amdgcn_s_waitcnt(0x0F70); }
__device__ __forceinline__ void wait_vm2() { __builtin_amdgcn_s_waitcnt(0x0F72); }

// ---------------- cast f32 -> bf16 ----------------
__global__ void cast_bf16_kernel(const float* __restrict__ in, ushort* __restrict__ out, int n4) {
  int i = blockIdx.x * blockDim.x + threadIdx.x;
  int stride = gridDim.x * blockDim.x;
  for (; i < n4; i += stride) {
    float4 v = reinterpret_cast<const float4*>(in)[i];
    ushort4 o;
    o.x = f2bf(v.x); o.y = f2bf(v.y); o.z = f2bf(v.z); o.w = f2bf(v.w);
    reinterpret_cast<ushort4*>(out)[i] = o;
  }
}

// ---------------- cast+permute W_ih: dst row hid*4+g <- src row g*HID+hid ----------------
__global__ void cast_permute_wih_kernel(const float* __restrict__ in, ushort* __restrict__ out) {
  int idx = blockIdx.x * 256 + threadIdx.x;     // over 4096 * 128
  int rowd = idx >> 7;
  int c8 = (idx & 127) << 3;
  int g = rowd & 3, hid = rowd >> 2;
  const float* src = in + ((size_t)g * HID + hid) * HID + c8;
  ushort* dst = out + (size_t)rowd * HID + c8;
#pragma unroll
  for (int i = 0; i < 8; ++i) dst[i] = f2bf(src[i]);
}

// ---------------- bias permute: out[hid*4+g] = bih[g*H+hid] + bhh[g*H+hid] ----------------
__global__ void bias_perm_kernel(const float* __restrict__ bih, const float* __restrict__ bhh,
                                 float* __restrict__ out) {
  int i = blockIdx.x * 256 + threadIdx.x;       // 4096
  int g = i & 3, hid = i >> 2;
  out[i] = bih[g * HID + hid] + bhh[g * HID + hid];
}

// ---------------- bf16 GEMM: C = act(A @ Bt^T + bias1 [+ bias2]) ----------------
// 128x128 tile, BK=64, 4 waves (2x2), m97 structure. XCD-swizzled blockIdx.
// If ovals != nullptr: fused decode epilogue (f32, masked, cols < ACTD; N==128).
__global__ __launch_bounds__(256) void gemm_bt_kernel(
    const ushort* __restrict__ A, const ushort* __restrict__ Bt,
    const float* __restrict__ bias1, const float* __restrict__ bias2,
    ushort* __restrict__ C, int M, int N, int K, int relu,
    const int* __restrict__ omask, float* __restrict__ ovals)
{
  __shared__ ushort la[128 * 64];   // 16 KB
  __shared__ ushort lb[128 * 64];   // 16 KB

  const int tid  = threadIdx.x;
  const int lane = tid & 63;
  const int w    = tid >> 6;
  const int wm   = w >> 1, wn = w & 1;
  const int nwg = gridDim.x;
  const int q8  = nwg >> 3;
  const int bid = (blockIdx.x & 7) * q8 + (blockIdx.x >> 3);
  const int ntiles = N >> 7;
  const int bm = bid / ntiles, bn = bid % ntiles;
  const size_t m0 = (size_t)bm << 7, n0 = (size_t)bn << 7;

  const int lrow = lane & 15;
  const int lk   = (lane >> 4) << 3;
  const int wavebase = (tid & ~63);

  f32x4_t acc[4][4];
  const f32x4_t zero = {0.f, 0.f, 0.f, 0.f};
#pragma unroll
  for (int i = 0; i < 4; ++i)
#pragma unroll
    for (int j = 0; j < 4; ++j) acc[i][j] = zero;

  for (int k0 = 0; k0 < K; k0 += 64) {
#pragma unroll
    for (int p = 0; p < 4; ++p) {
      int c = p * 256 + tid;
      int r = c >> 3;
      int q = (c & 7) << 3;
      gl_lds16(A + (m0 + r) * (size_t)K + k0 + q, la + (size_t)(p * 256 + wavebase) * 8);
      gl_lds16(Bt + (n0 + r) * (size_t)K + k0 + q, lb + (size_t)(p * 256 + wavebase) * 8);
    }
    __syncthreads();
#pragma unroll
    for (int kk = 0; kk < 64; kk += 32) {
      bf16x8_t af[4], bfr[4];
#pragma unroll
      for (int i = 0; i < 4; ++i)
        af[i] = *(const bf16x8_t*)(la + (wm * 64 + i * 16 + lrow) * 64 + kk + lk);
#pragma unroll
      for (int j = 0; j < 4; ++j)
        bfr[j] = *(const bf16x8_t*)(lb + (wn * 64 + j * 16 + lrow) * 64 + kk + lk);
#pragma unroll
      for (int i = 0; i < 4; ++i)
#pragma unroll
        for (int j = 0; j < 4; ++j)
          acc[i][j] = mfma16(af[i], bfr[j], acc[i][j]);
    }
    __syncthreads();
  }

  const int crow0 = (lane >> 4) * 4;
  if (ovals) {
#pragma unroll
    for (int j = 0; j < 4; ++j) {
      int col = wn * 64 + j * 16 + lrow;
      if (col < ACTD) {
        float bv = bias1[col];
#pragma unroll
        for (int i = 0; i < 4; ++i) {
#pragma unroll
          for (int r = 0; r < 4; ++r) {
            size_t row = m0 + wm * 64 + i * 16 + crow0 + r;
            float mv = (float)omask[row];
            ovals[row * ACTD + col] = (acc[i][j][r] + bv) * mv;
          }
        }
      }
    }
    return;
  }
#pragma unroll
  for (int j = 0; j < 4; ++j) {
    int col = (int)n0 + wn * 64 + j * 16 + lrow;
    float bv = bias1 ? bias1[col] : 0.f;
    if (bias2) bv += bias2[col];
#pragma unroll
    for (int i = 0; i < 4; ++i) {
#pragma unroll
      for (int r = 0; r < 4; ++r) {
        size_t row = m0 + wm * 64 + i * 16 + crow0 + r;
        float v = acc[i][j][r] + bv;
        if (relu) v = fmaxf(v, 0.f);
        C[row * (size_t)N + col] = f2bf(v);
      }
    }
  }
}

// ---------------- persistent LSTM scan (chunk [t0, t0+nsteps)) ----------------
// 256 WGs = 4 batch quarters x 64 j-slices (16 hidden each).
// Fence-free cross-XCD protocol:
//   h stores  : LDS-bounce + 8B relaxed agent atomic stores (sc0 sc1, write-through
//               to LLC) -> no buffer_wbl2 per step.
//   flag store: relaxed agent atomic after __syncthreads (vmcnt0 orders h stores).
//   barrier   : hierarchical (8 leaders x 32 members, then 8 leader flags),
//               ~2300 poll loads/sweep instead of 65536.
//   acquire   : ONE acquire load per WG per step (buffer_inv) so the cached
//               global_load_lds staging path reads fresh h from LLC.
__global__ __launch_bounds__(256, 1) void lstm_scan_kernel(
    const ushort* __restrict__ xg,      // (nsteps,B,4H) bf16, gate-permuted
    const ushort* __restrict__ whh,     // (4H,H) bf16 natural
    const int* __restrict__ mask,       // (nsteps,B) (pre-offset)
    ushort* __restrict__ hbuf,          // (2,B,H) bf16 (zeroed at start)
    ushort* __restrict__ latent,        // (nsteps,B,H) bf16
    float* __restrict__ cbuf,           // (B,H) f32 persistent cell state
    float* __restrict__ outh, float* __restrict__ outc,   // (B,H) f32
    unsigned* __restrict__ flags,       // (256+8) x 16 uints, zeroed per launch
    int t0, int nsteps)
{
  __shared__ ushort lwh[64 * 1024];     // 128 KB, granule-XOR-swizzled
  __shared__ ushort hst[3 * 4096];      // 3 x 8 KB h staging
  __shared__ ushort hexch[32 * 16];     // 1 KB h exchange bounce

  const int tid  = threadIdx.x;
  const int lane = tid & 63;
  const int w    = tid >> 6;
  const int wg   = blockIdx.x;
  const int bq   = wg >> 6;            // batch quarter 0..3
  const int jg   = wg & 63;            // j slice
  const int j0   = jg * JG;
  const int b0   = bq * 32;

  // Gather W_hh slice, row rr = jj*4+g <- whh row g*H + j0+jj, granule-swizzled.
  for (int c = tid; c < 64 * 128; c += 256) {
    int r = c >> 7, gn = c & 127;
    int jj = r >> 2, g = r & 3;
    const ushort* src = whh + ((size_t)g * HID + j0 + jj) * HID + gn * 8;
    int gnd = (gn & ~7) | ((gn & 7) ^ (r & 7));
    *reinterpret_cast<uint4*>(&lwh[r * 1024 + gnd * 8]) =
        *reinterpret_cast<const uint4*>(src);
  }
  __syncthreads();

  const int lrow = lane & 15;
  const int lkg  = lane >> 4;

  // cell mapping: jjc = w*4+lkg; local batch rows bl0 = lrow, bl1 = 16+lrow
  const int jjc = w * 4 + lkg;
  const int bl0 = lrow, bl1 = 16 + lrow;

  float creg0, creg1;
  if (t0 == 0) { creg0 = creg1 = 0.f; }
  else {
    creg0 = cbuf[(size_t)(b0 + bl0) * HID + j0 + jjc];
    creg1 = cbuf[(size_t)(b0 + bl1) * HID + j0 + jjc];
  }

  int cur = t0 & 1;

  // staging DMA constants: slots s0 = w*128+lane (instr0), s1 = s0+64 (instr1)
  const int s0 = w * 128 + lane;
  const int s1 = s0 + 64;
  const int sb0 = s0 >> 4, sq0 = s0 & 15;
  const int sb1 = s1 >> 4, sq1 = s1 & 15;
  const int gg0 = (sq0 & 8) | ((sq0 & 7) ^ (sb0 & 7));   // source granule (swizzle inverse)
  const int gg1 = (sq1 & 8) | ((sq1 & 7) ^ (sb1 & 7));

  // prefetch xg/mask for step 0
  ushort4 xv0, xv1;
  float m0v, m1v;
  {
    xv0 = *(const ushort4*)(xg + (size_t)(b0 + bl0) * GH + (j0 + jjc) * 4);
    xv1 = *(const ushort4*)(xg + (size_t)(b0 + bl1) * GH + (j0 + jjc) * 4);
    m0v = (float)mask[b0 + bl0];
    m1v = (float)mask[b0 + bl1];
  }
  __builtin_amdgcn_sched_barrier(0);

  for (int tl = 0; tl < nsteps; ++tl) {
    const ushort* hsrc = hbuf + (size_t)cur * (BATCH * HID) + (size_t)b0 * HID;

    wait_vm0();                          // clean vmcnt slate (prefetch drained)
    __builtin_amdgcn_sched_barrier(0);

    f32x4_t acc0 = {0.f, 0.f, 0.f, 0.f};
    f32x4_t acc1 = {0.f, 0.f, 0.f, 0.f};

    // prologue: stage chunks 0,1
#pragma unroll
    for (int kc = 0; kc < 2; ++kc) {
      gl_lds16(hsrc + (size_t)sb0 * HID + (kc * 16 + gg0) * 8, hst + (size_t)kc * 4096 + (size_t)(w * 128) * 8);
      gl_lds16(hsrc + (size_t)sb1 * HID + (kc * 16 + gg1) * 8, hst + (size_t)kc * 4096 + (size_t)(w * 128 + 64) * 8);
    }
    __builtin_amdgcn_sched_barrier(0);

#pragma unroll
    for (int kc = 0; kc < 8; ++kc) {
      if (kc < 7) wait_vm2(); else wait_vm0();
      __builtin_amdgcn_s_barrier();
      __builtin_amdgcn_sched_barrier(0);
      const ushort* sbuf = hst + (size_t)(kc % 3) * 4096;
#pragma unroll
      for (int ks = 0; ks < 4; ++ks) {
        int gA = kc * 16 + ks * 4 + lkg;
        int gAs = (gA & ~7) | ((gA & 7) ^ (lrow & 7));   // (w*16+lrow)&7 == lrow&7
        bf16x8_t af = *(const bf16x8_t*)(lwh + (size_t)(w * 16 + lrow) * 1024 + gAs * 8);
        int q16 = ks * 4 + lkg;
        int qs = (q16 & 8) | ((q16 & 7) ^ (bl0 & 7));    // bl1&7 == bl0&7
        bf16x8_t bf0 = *(const bf16x8_t*)(sbuf + (size_t)bl0 * 128 + qs * 8);
        bf16x8_t bf1 = *(const bf16x8_t*)(sbuf + (size_t)bl1 * 128 + qs * 8);
        acc0 = mfma16(af, bf0, acc0);
        acc1 = mfma16(af, bf1, acc1);
      }
      if (kc < 6) {
        int kn = kc + 2;
        int p = kn % 3;
        gl_lds16(hsrc + (size_t)sb0 * HID + (kn * 16 + gg0) * 8, hst + (size_t)p * 4096 + (size_t)(w * 128) * 8);
        gl_lds16(hsrc + (size_t)sb1 * HID + (kn * 16 + gg1) * 8, hst + (size_t)p * 4096 + (size_t)(w * 128 + 64) * 8);
      }
      __builtin_amdgcn_sched_barrier(0);
    }

    // ---- epilogue: fragment-native nonlinearities (lane owns 2 cells) ----
    {
      float ig = sigm(acc0[0] + bf2f(xv0.x));
      float fg = sigm(acc0[1] + bf2f(xv0.y));
      float gt = tanhf_fast(acc0[2] + bf2f(xv0.z));
      float og = sigm(acc0[3] + bf2f(xv0.w));
      float cp = fg * creg0 + ig * gt;
      creg0 = cp * m0v;
      float h0 = og * tanhf_fast(cp) * m0v;

      ig = sigm(acc1[0] + bf2f(xv1.x));
      fg = sigm(acc1[1] + bf2f(xv1.y));
      gt = tanhf_fast(acc1[2] + bf2f(xv1.z));
      og = sigm(acc1[3] + bf2f(xv1.w));
      cp = fg * creg1 + ig * gt;
      creg1 = cp * m1v;
      float h1 = og * tanhf_fast(cp) * m1v;

      ushort hb0 = f2bf(h0), hb1 = f2bf(h1);
      // bounce h through LDS for coalesced 8B coherent stores
      hexch[bl0 * 16 + jjc] = hb0;
      hexch[bl1 * 16 + jjc] = hb1;
      // latent: normal cached stores (read only after kernel end)
      ushort* ldst = latent + (size_t)tl * BATCH * HID;
      ldst[(size_t)(b0 + bl0) * HID + j0 + jjc] = hb0;
      ldst[(size_t)(b0 + bl1) * HID + j0 + jjc] = hb1;
      if (t0 + tl == T_STEPS - 1) {
        outh[(size_t)(b0 + bl0) * HID + j0 + jjc] = h0;
        outh[(size_t)(b0 + bl1) * HID + j0 + jjc] = h1;
        outc[(size_t)(b0 + bl0) * HID + j0 + jjc] = creg0;
        outc[(size_t)(b0 + bl1) * HID + j0 + jjc] = creg1;
      }
    }
    __syncthreads();                     // hexch complete (lgkm)

    // device-coherent 8B h stores (write-through to LLC, no fence needed)
    if (tid < 128) {
      int bl = tid >> 2, seg = tid & 3;
      unsigned long long v = *(const unsigned long long*)(&hexch[bl * 16 + seg * 4]);
      unsigned long long* dst = (unsigned long long*)(hbuf +
          (size_t)(cur ^ 1) * (BATCH * HID) + (size_t)(b0 + bl) * HID + j0 + seg * 4);
      __hip_atomic_store(dst, v, __ATOMIC_RELAXED, __HIP_MEMORY_SCOPE_AGENT);
    }

    // ---- hierarchical fence-free grid barrier (skip after last local step) ----
    if (tl != nsteps - 1) {
      __syncthreads();                   // all h atomic stores complete (vmcnt0/wave)
      const unsigned tgt = (unsigned)(t0 + tl + 1);
      if (tid == 0)
        __hip_atomic_store(&flags[(size_t)wg * 16], tgt, __ATOMIC_RELAXED, __HIP_MEMORY_SCOPE_AGENT);
      // overlap: prefetch next step's xg + mask (immutable -> cache staleness ok)
      {
        const ushort* xp = xg + (size_t)(tl + 1) * BATCH * GH;
        xv0 = *(const ushort4*)(xp + (size_t)(b0 + bl0) * GH + (j0 + jjc) * 4);
        xv1 = *(const ushort4*)(xp + (size_t)(b0 + bl1) * GH + (j0 + jjc) * 4);
        m0v = (float)mask[(tl + 1) * BATCH + b0 + bl0];
        m1v = (float)mask[(tl + 1) * BATCH + b0 + bl1];
      }
      __builtin_amdgcn_sched_barrier(0);
      // leaders (wg<8): aggregate 32 member flags {wg, wg+8, ..., wg+248}
      if (wg < 8) {
        if (tid < 32) {
          for (;;) {
            unsigned v = __hip_atomic_load(&flags[(size_t)(wg + tid * 8) * 16],
                                           __ATOMIC_RELAXED, __HIP_MEMORY_SCOPE_AGENT);
            if (__all(v >= tgt)) break;
          }
        }
        if (tid == 0)
          __hip_atomic_store(&flags[(size_t)(NWG + wg) * 16], tgt,
                             __ATOMIC_RELAXED, __HIP_MEMORY_SCOPE_AGENT);
      }
      // everyone: poll the 8 leader flags
      if (tid < 8) {
        for (;;) {
          unsigned v = __hip_atomic_load(&flags[(size_t)(NWG + tid) * 16],
                                         __ATOMIC_RELAXED, __HIP_MEMORY_SCOPE_AGENT);
          if (__all(v >= tgt)) break;
        }
      }
      // single acquire -> buffer_inv: subsequent cached h loads refill from LLC
      if (tid == 0)
        (void)__hip_atomic_load(&flags[(size_t)NWG * 16], __ATOMIC_ACQUIRE, __HIP_MEMORY_SCOPE_AGENT);
      __syncthreads();
    }
    cur ^= 1;
  }

  // persist cell state for next chunk
  cbuf[(size_t)(b0 + bl0) * HID + j0 + jjc] = creg0;
  cbuf[(size_t)(b0 + bl1) * HID + j0 + jjc] = creg1;
}

extern "C" void kernel_launch(void* const* d_in, const int* in_sizes, int n_in,
                              void* d_out, int out_size, void* d_ws, size_t ws_size,
                              hipStream_t stream) {
  (void)in_sizes; (void)n_in; (void)out_size;
  const float* state = (const float*)d_in[0];
  const int*   mask  = (const int*)d_in[1];
  const float* Wenc  = (const float*)d_in[2];
  const float* benc  = (const float*)d_in[3];
  const float* Wih   = (const float*)d_in[4];
  const float* Whh   = (const float*)d_in[5];
  const float* bih   = (const float*)d_in[6];
  const float* bhh   = (const float*)d_in[7];
  const float* Wdec  = (const float*)d_in[8];
  const float* bdec  = (const float*)d_in[9];

  float* out_values = (float*)d_out;                       // T*B*A
  float* out_h = out_values + (size_t)TBROWS * ACTD;       // B*H
  float* out_c = out_h + (size_t)BATCH * HID;              // B*H

  auto pad256 = [](size_t b) { return (b + 255) & ~(size_t)255; };

  const size_t sz_wenc  = (size_t)HID * OBSD * 2;
  const size_t sz_wih   = (size_t)GH * HID * 2;
  const size_t sz_whh   = (size_t)GH * HID * 2;
  const size_t sz_wdec  = (size_t)128 * HID * 2;
  const size_t sz_bdec  = 512;
  const size_t sz_bperm = (size_t)GH * sizeof(float);
  const size_t sz_flags = (NWG + 8) * 16 * sizeof(unsigned);
  const size_t sz_hbuf  = (size_t)2 * BATCH * HID * 2;
  const size_t sz_cbuf  = (size_t)BATCH * HID * 4;
  const size_t fixed = pad256(sz_wenc) + pad256(sz_wih) + pad256(sz_whh) +
                       pad256(sz_wdec) + pad256(sz_bdec) + pad256(sz_bperm) +
                       pad256(sz_flags) + pad256(sz_hbuf) + pad256(sz_cbuf);

  int Tc = 8;
  {
    const int cands[6] = {256, 128, 64, 32, 16, 8};
    for (int ci = 0; ci < 6; ++ci) {
      int tc = cands[ci];
      size_t per = pad256((size_t)tc * BATCH * OBSD * 2)
                 + pad256((size_t)tc * BATCH * HID * 2)
                 + pad256((size_t)tc * BATCH * GH * 2)
                 + pad256((size_t)tc * BATCH * HID * 2);
      if (fixed + per <= ws_size) { Tc = tc; break; }
    }
  }
  const int nchunks = T_STEPS / Tc;
  const int crows = Tc * BATCH;

  char* ws = (char*)d_ws;
  size_t off = 0;
  auto alloc = [&](size_t b) { char* r = ws + off; off += pad256(b); return r; };
  ushort* wenc_bf  = (ushort*)alloc(sz_wenc);
  ushort* wih_perm = (ushort*)alloc(sz_wih);
  ushort* whh_bf   = (ushort*)alloc(sz_whh);
  ushort* wdec_pad = (ushort*)alloc(sz_wdec);
  float*  bdec_pad = (float*)alloc(sz_bdec);
  float*  bperm    = (float*)alloc(sz_bperm);
  unsigned* flags  = (unsigned*)alloc(sz_flags);
  ushort* hbuf     = (ushort*)alloc(sz_hbuf);
  float*  cbuf     = (float*)alloc(sz_cbuf);
  ushort* state_c  = (ushort*)alloc((size_t)crows * OBSD * 2);
  ushort* enc_c    = (ushort*)alloc((size_t)crows * HID * 2);
  ushort* xg_c     = (ushort*)alloc((size_t)crows * GH * 2);
  ushort* lat_c    = (ushort*)alloc((size_t)crows * HID * 2);

  hipMemsetAsync(hbuf, 0, sz_hbuf, stream);
  hipMemsetAsync(flags, 0, sz_flags, stream);
  hipMemsetAsync(wdec_pad, 0, sz_wdec, stream);
  hipMemsetAsync(bdec_pad, 0, sz_bdec, stream);
  hipMemcpyAsync(bdec_pad, bdec, ACTD * sizeof(float), hipMemcpyDeviceToDevice, stream);

  auto cast = [&](const float* src, ushort* dst, size_t n) {
    int n4 = (int)(n / 4);
    int blocks = (n4 + 255) / 256;
    if (blocks > 4096) blocks = 4096;
    cast_bf16_kernel<<<blocks, 256, 0, stream>>>(src, dst, n4);
  };
  cast(Wenc, wenc_bf, (size_t)HID * OBSD);
  cast(Whh, whh_bf, (size_t)GH * HID);
  cast(Wdec, wdec_pad, (size_t)ACTD * HID);
  cast_permute_wih_kernel<<<(GH * 128) / 256, 256, 0, stream>>>(Wih, wih_perm);
  bias_perm_kernel<<<GH / 256, 256, 0, stream>>>(bih, bhh, bperm);

  for (int c = 0; c < nchunks; ++c) {
    const int t0 = c * Tc;
    cast(state + (size_t)t0 * BATCH * OBSD, state_c, (size_t)crows * OBSD);
    // encode: relu(state @ Wenc^T + b_enc)
    gemm_bt_kernel<<<(crows / 128) * (HID / 128), 256, 0, stream>>>(
        state_c, wenc_bf, benc, nullptr, enc_c, crows, HID, OBSD, 1, nullptr, nullptr);
    // x-gates (gate-permuted cols): enc @ Wih_perm^T + bperm
    gemm_bt_kernel<<<(crows / 128) * (GH / 128), 256, 0, stream>>>(
        enc_c, wih_perm, bperm, nullptr, xg_c, crows, GH, HID, 0, nullptr, nullptr);
    // sequential scan over this chunk
    lstm_scan_kernel<<<NWG, 256, 0, stream>>>(
        xg_c, whh_bf, mask + (size_t)t0 * BATCH, hbuf, lat_c, cbuf,
        out_h, out_c, flags, t0, Tc);
    // fused decode + mask + extract
    gemm_bt_kernel<<<crows / 128, 256, 0, stream>>>(
        lat_c, wdec_pad, bdec_pad, nullptr, nullptr, crows, 128, HID, 0,
        mask + (size_t)t0 * BATCH, out_values + (size_t)t0 * BATCH * ACTD);
  }
}

// Round 6
// 2244.857 us; speedup vs baseline: 2.9374x; 1.1469x over previous
//
#include <hip/hip_runtime.h>

#define T_STEPS 256
#define BATCH   128
#define OBSD    512
#define HID     1024
#define GH      4096
#define ACTD    18
#define TBROWS  (T_STEPS*BATCH)   // 32768
#define NWG     256               // scan WGs: 4 batch quarters x 64 j-slices
#define JG      16                // hidden units per scan WG

typedef __bf16 bf16x8_t __attribute__((ext_vector_type(8)));
typedef float  f32x4_t  __attribute__((ext_vector_type(4)));

__device__ __forceinline__ ushort f2bf(float f) {
  unsigned u = __builtin_bit_cast(unsigned, f);
  u += 0x7fffu + ((u >> 16) & 1u);          // RNE
  return (ushort)(u >> 16);
}
__device__ __forceinline__ float bf2f(ushort s) {
  return __builtin_bit_cast(float, ((unsigned)s) << 16);
}
__device__ __forceinline__ f32x4_t mfma16(bf16x8_t a, bf16x8_t b, f32x4_t c) {
  return __builtin_amdgcn_mfma_f32_16x16x32_bf16(a, b, c, 0, 0, 0);
}
__device__ __forceinline__ void gl_lds16(const void* g, void* l) {
  __builtin_amdgcn_global_load_lds(
      (__attribute__((address_space(1))) void*)(g),
      (__attribute__((address_space(3))) void*)(l), 16, 0, 0);
}
__device__ __forceinline__ float sigm(float x) { return 1.f / (1.f + __expf(-x)); }
__device__ __forceinline__ float tanhf_fast(float x) {
  float e = __expf(2.f * x);
  return (e - 1.f) / (e + 1.f);
}
// vmcnt-only wait (lgkm=15/exp=7 fields = no-wait)
__device__ __forceinline__ void wait_vm0() { __builtin_amdgcn_s_waitcnt(0x0F70); }

// ---------------- cast f32 -> bf16 ----------------
__global__ void cast_bf16_kernel(const float* __restrict__ in, ushort* __restrict__ out, int n4) {
  int i = blockIdx.x * blockDim.x + threadIdx.x;
  int stride = gridDim.x * blockDim.x;
  for (; i < n4; i += stride) {
    float4 v = reinterpret_cast<const float4*>(in)[i];
    ushort4 o;
    o.x = f2bf(v.x); o.y = f2bf(v.y); o.z = f2bf(v.z); o.w = f2bf(v.w);
    reinterpret_cast<ushort4*>(out)[i] = o;
  }
}

// ---------------- cast+permute W_ih: dst row hid*4+g <- src row g*HID+hid ----------------
__global__ void cast_permute_wih_kernel(const float* __restrict__ in, ushort* __restrict__ out) {
  int idx = blockIdx.x * 256 + threadIdx.x;     // over 4096 * 128
  int rowd = idx >> 7;
  int c8 = (idx & 127) << 3;
  int g = rowd & 3, hid = rowd >> 2;
  const float* src = in + ((size_t)g * HID + hid) * HID + c8;
  ushort* dst = out + (size_t)rowd * HID + c8;
#pragma unroll
  for (int i = 0; i < 8; ++i) dst[i] = f2bf(src[i]);
}

// ---------------- bias permute: out[hid*4+g] = bih[g*H+hid] + bhh[g*H+hid] ----------------
__global__ void bias_perm_kernel(const float* __restrict__ bih, const float* __restrict__ bhh,
                                 float* __restrict__ out) {
  int i = blockIdx.x * 256 + threadIdx.x;       // 4096
  int g = i & 3, hid = i >> 2;
  out[i] = bih[g * HID + hid] + bhh[g * HID + hid];
}

// ---------------- bf16 GEMM: C = act(A @ Bt^T + bias1 [+ bias2]) ----------------
// 128x128 tile, BK=64, 4 waves (2x2), m97 structure. XCD-swizzled blockIdx.
// If ovals != nullptr: fused decode epilogue (f32, masked, cols < ACTD; N==128).
__global__ __launch_bounds__(256) void gemm_bt_kernel(
    const ushort* __restrict__ A, const ushort* __restrict__ Bt,
    const float* __restrict__ bias1, const float* __restrict__ bias2,
    ushort* __restrict__ C, int M, int N, int K, int relu,
    const int* __restrict__ omask, float* __restrict__ ovals)
{
  __shared__ ushort la[128 * 64];   // 16 KB
  __shared__ ushort lb[128 * 64];   // 16 KB

  const int tid  = threadIdx.x;
  const int lane = tid & 63;
  const int w    = tid >> 6;
  const int wm   = w >> 1, wn = w & 1;
  const int nwg = gridDim.x;
  const int q8  = nwg >> 3;
  const int bid = (blockIdx.x & 7) * q8 + (blockIdx.x >> 3);
  const int ntiles = N >> 7;
  const int bm = bid / ntiles, bn = bid % ntiles;
  const size_t m0 = (size_t)bm << 7, n0 = (size_t)bn << 7;

  const int lrow = lane & 15;
  const int lk   = (lane >> 4) << 3;
  const int wavebase = (tid & ~63);

  f32x4_t acc[4][4];
  const f32x4_t zero = {0.f, 0.f, 0.f, 0.f};
#pragma unroll
  for (int i = 0; i < 4; ++i)
#pragma unroll
    for (int j = 0; j < 4; ++j) acc[i][j] = zero;

  for (int k0 = 0; k0 < K; k0 += 64) {
#pragma unroll
    for (int p = 0; p < 4; ++p) {
      int c = p * 256 + tid;
      int r = c >> 3;
      int q = (c & 7) << 3;
      gl_lds16(A + (m0 + r) * (size_t)K + k0 + q, la + (size_t)(p * 256 + wavebase) * 8);
      gl_lds16(Bt + (n0 + r) * (size_t)K + k0 + q, lb + (size_t)(p * 256 + wavebase) * 8);
    }
    __syncthreads();
#pragma unroll
    for (int kk = 0; kk < 64; kk += 32) {
      bf16x8_t af[4], bfr[4];
#pragma unroll
      for (int i = 0; i < 4; ++i)
        af[i] = *(const bf16x8_t*)(la + (wm * 64 + i * 16 + lrow) * 64 + kk + lk);
#pragma unroll
      for (int j = 0; j < 4; ++j)
        bfr[j] = *(const bf16x8_t*)(lb + (wn * 64 + j * 16 + lrow) * 64 + kk + lk);
#pragma unroll
      for (int i = 0; i < 4; ++i)
#pragma unroll
        for (int j = 0; j < 4; ++j)
          acc[i][j] = mfma16(af[i], bfr[j], acc[i][j]);
    }
    __syncthreads();
  }

  const int crow0 = (lane >> 4) * 4;
  if (ovals) {
#pragma unroll
    for (int j = 0; j < 4; ++j) {
      int col = wn * 64 + j * 16 + lrow;
      if (col < ACTD) {
        float bv = bias1[col];
#pragma unroll
        for (int i = 0; i < 4; ++i) {
#pragma unroll
          for (int r = 0; r < 4; ++r) {
            size_t row = m0 + wm * 64 + i * 16 + crow0 + r;
            float mv = (float)omask[row];
            ovals[row * ACTD + col] = (acc[i][j][r] + bv) * mv;
          }
        }
      }
    }
    return;
  }
#pragma unroll
  for (int j = 0; j < 4; ++j) {
    int col = (int)n0 + wn * 64 + j * 16 + lrow;
    float bv = bias1 ? bias1[col] : 0.f;
    if (bias2) bv += bias2[col];
#pragma unroll
    for (int i = 0; i < 4; ++i) {
#pragma unroll
      for (int r = 0; r < 4; ++r) {
        size_t row = m0 + wm * 64 + i * 16 + crow0 + r;
        float v = acc[i][j][r] + bv;
        if (relu) v = fmaxf(v, 0.f);
        C[row * (size_t)N + col] = f2bf(v);
      }
    }
  }
}

// ---------------- persistent LSTM scan (chunk [t0, t0+nsteps)) ----------------
// 256 WGs = 4 batch quarters x 64 j-slices (16 hidden each).
// NEW (r6): W_hh fragments live in 128 VGPRs/lane (af[8][4], hoisted once via an
// LDS bounce); the 128 KB LDS is then REUSED as 8 x 8 KB h staging buffers, so
// each step issues all 16 global_load_lds up-front and pays LLC latency once.
// Fence-free cross-XCD protocol (proven r5): coherent 8B h stores (write-through
// LLC), relaxed flag after syncthreads-drain, hierarchical barrier, one acquire.
__global__ __launch_bounds__(256, 1) void lstm_scan_kernel(
    const ushort* __restrict__ xg,      // (nsteps,B,4H) bf16, gate-permuted
    const ushort* __restrict__ whh,     // (4H,H) bf16 natural
    const int* __restrict__ mask,       // (nsteps,B) (pre-offset)
    ushort* __restrict__ hbuf,          // (2,B,H) bf16 (zeroed at start)
    ushort* __restrict__ latent,        // (nsteps,B,H) bf16
    float* __restrict__ cbuf,           // (B,H) f32 persistent cell state
    float* __restrict__ outh, float* __restrict__ outc,   // (B,H) f32
    unsigned* __restrict__ flags,       // (256+8) x 16 uints, zeroed per launch
    int t0, int nsteps)
{
  __shared__ __align__(16) ushort lds_pool[64 * 1024];  // 128 KB: W gather, then 8x8KB staging
  __shared__ __align__(16) ushort hexch[32 * 16];       // 1 KB h exchange bounce

  const int tid  = threadIdx.x;
  const int lane = tid & 63;
  const int w    = tid >> 6;
  const int wg   = blockIdx.x;
  const int bq   = wg >> 6;            // batch quarter 0..3
  const int jg   = wg & 63;            // j slice
  const int j0   = jg * JG;
  const int b0   = bq * 32;

  const int lrow = lane & 15;
  const int lkg  = lane >> 4;

  // ---- phase A: gather W_hh slice into LDS (row rr = jj*4+g, granule-swizzled) ----
  for (int c = tid; c < 64 * 128; c += 256) {
    int r = c >> 7, gn = c & 127;
    int jj = r >> 2, g = r & 3;
    const ushort* src = whh + ((size_t)g * HID + j0 + jj) * HID + gn * 8;
    int gnd = (gn & ~7) | ((gn & 7) ^ (r & 7));
    *reinterpret_cast<uint4*>(&lds_pool[r * 1024 + gnd * 8]) =
        *reinterpret_cast<const uint4*>(src);
  }
  __syncthreads();

  // ---- phase B: extract this wave's A-fragments to registers (128 VGPR/lane) ----
  bf16x8_t af[8][4];
#pragma unroll
  for (int kc = 0; kc < 8; ++kc) {
#pragma unroll
    for (int ks = 0; ks < 4; ++ks) {
      int gA = kc * 16 + ks * 4 + lkg;
      int gAs = (gA & ~7) | ((gA & 7) ^ (lrow & 7));
      af[kc][ks] = *(const bf16x8_t*)(lds_pool + (size_t)(w * 16 + lrow) * 1024 + gAs * 8);
    }
  }
  __syncthreads();                      // all reads done before staging overwrites
  ushort* hstg = lds_pool;              // 8 buffers x 4096 ushorts (64 KB used)

  // cell mapping: jjc = w*4+lkg; local batch rows bl0 = lrow, bl1 = 16+lrow
  const int jjc = w * 4 + lkg;
  const int bl0 = lrow, bl1 = 16 + lrow;

  float creg0, creg1;
  if (t0 == 0) { creg0 = creg1 = 0.f; }
  else {
    creg0 = cbuf[(size_t)(b0 + bl0) * HID + j0 + jjc];
    creg1 = cbuf[(size_t)(b0 + bl1) * HID + j0 + jjc];
  }

  int cur = t0 & 1;

  // staging DMA constants: slots s0 = w*128+lane (instr0), s1 = s0+64 (instr1)
  const int s0 = w * 128 + lane;
  const int s1 = s0 + 64;
  const int sb0 = s0 >> 4, sq0 = s0 & 15;
  const int sb1 = s1 >> 4, sq1 = s1 & 15;
  const int gg0 = (sq0 & 8) | ((sq0 & 7) ^ (sb0 & 7));   // source granule (swizzle inverse)
  const int gg1 = (sq1 & 8) | ((sq1 & 7) ^ (sb1 & 7));

  // prefetch xg/mask for step 0
  ushort4 xv0, xv1;
  float m0v, m1v;
  {
    xv0 = *(const ushort4*)(xg + (size_t)(b0 + bl0) * GH + (j0 + jjc) * 4);
    xv1 = *(const ushort4*)(xg + (size_t)(b0 + bl1) * GH + (j0 + jjc) * 4);
    m0v = (float)mask[b0 + bl0];
    m1v = (float)mask[b0 + bl1];
  }
  __builtin_amdgcn_sched_barrier(0);

#define CHUNK(KC, VN) do {                                                     \
    __builtin_amdgcn_s_waitcnt(0x0F70 | (VN));                                 \
    __builtin_amdgcn_s_barrier();                                              \
    __builtin_amdgcn_sched_barrier(0);                                         \
    const ushort* sbuf = hstg + (size_t)(KC) * 4096;                           \
    _Pragma("unroll")                                                          \
    for (int ks = 0; ks < 4; ++ks) {                                           \
      int q16 = ks * 4 + lkg;                                                  \
      int qs = (q16 & 8) | ((q16 & 7) ^ (bl0 & 7));                            \
      bf16x8_t bf0 = *(const bf16x8_t*)(sbuf + (size_t)bl0 * 128 + qs * 8);    \
      bf16x8_t bf1 = *(const bf16x8_t*)(sbuf + (size_t)bl1 * 128 + qs * 8);    \
      acc0 = mfma16(af[KC][ks], bf0, acc0);                                    \
      acc1 = mfma16(af[KC][ks], bf1, acc1);                                    \
    }                                                                          \
    __builtin_amdgcn_sched_barrier(0);                                         \
  } while (0)

  for (int tl = 0; tl < nsteps; ++tl) {
    const ushort* hsrc = hbuf + (size_t)cur * (BATCH * HID) + (size_t)b0 * HID;

    wait_vm0();                          // clean vmcnt slate
    __builtin_amdgcn_sched_barrier(0);

    f32x4_t acc0 = {0.f, 0.f, 0.f, 0.f};
    f32x4_t acc1 = {0.f, 0.f, 0.f, 0.f};

    // issue ALL 16 staging loads (8 chunks x 2) back-to-back
#pragma unroll
    for (int kc = 0; kc < 8; ++kc) {
      gl_lds16(hsrc + (size_t)sb0 * HID + (kc * 16 + gg0) * 8,
               hstg + (size_t)kc * 4096 + (size_t)(w * 128) * 8);
      gl_lds16(hsrc + (size_t)sb1 * HID + (kc * 16 + gg1) * 8,
               hstg + (size_t)kc * 4096 + (size_t)(w * 128 + 64) * 8);
    }
    __builtin_amdgcn_sched_barrier(0);

    CHUNK(0, 14); CHUNK(1, 12); CHUNK(2, 10); CHUNK(3, 8);
    CHUNK(4, 6);  CHUNK(5, 4);  CHUNK(6, 2);  CHUNK(7, 0);

    // ---- epilogue: fragment-native nonlinearities (lane owns 2 cells) ----
    {
      float ig = sigm(acc0[0] + bf2f(xv0.x));
      float fg = sigm(acc0[1] + bf2f(xv0.y));
      float gt = tanhf_fast(acc0[2] + bf2f(xv0.z));
      float og = sigm(acc0[3] + bf2f(xv0.w));
      float cp = fg * creg0 + ig * gt;
      creg0 = cp * m0v;
      float h0 = og * tanhf_fast(cp) * m0v;

      ig = sigm(acc1[0] + bf2f(xv1.x));
      fg = sigm(acc1[1] + bf2f(xv1.y));
      gt = tanhf_fast(acc1[2] + bf2f(xv1.z));
      og = sigm(acc1[3] + bf2f(xv1.w));
      cp = fg * creg1 + ig * gt;
      creg1 = cp * m1v;
      float h1 = og * tanhf_fast(cp) * m1v;

      ushort hb0 = f2bf(h0), hb1 = f2bf(h1);
      // bounce h through LDS for coalesced 8B coherent stores
      hexch[bl0 * 16 + jjc] = hb0;
      hexch[bl1 * 16 + jjc] = hb1;
      // latent: normal cached stores (read only after kernel end)
      ushort* ldst = latent + (size_t)tl * BATCH * HID;
      ldst[(size_t)(b0 + bl0) * HID + j0 + jjc] = hb0;
      ldst[(size_t)(b0 + bl1) * HID + j0 + jjc] = hb1;
      if (t0 + tl == T_STEPS - 1) {
        outh[(size_t)(b0 + bl0) * HID + j0 + jjc] = h0;
        outh[(size_t)(b0 + bl1) * HID + j0 + jjc] = h1;
        outc[(size_t)(b0 + bl0) * HID + j0 + jjc] = creg0;
        outc[(size_t)(b0 + bl1) * HID + j0 + jjc] = creg1;
      }
    }
    __syncthreads();                     // hexch complete (lgkm)

    // device-coherent 8B h stores (write-through to LLC, no fence needed)
    if (tid < 128) {
      int bl = tid >> 2, seg = tid & 3;
      unsigned long long v = *(const unsigned long long*)(&hexch[bl * 16 + seg * 4]);
      unsigned long long* dst = (unsigned long long*)(hbuf +
          (size_t)(cur ^ 1) * (BATCH * HID) + (size_t)(b0 + bl) * HID + j0 + seg * 4);
      __hip_atomic_store(dst, v, __ATOMIC_RELAXED, __HIP_MEMORY_SCOPE_AGENT);
    }

    // ---- hierarchical fence-free grid barrier (skip after last local step) ----
    if (tl != nsteps - 1) {
      __syncthreads();                   // all h atomic stores complete (vmcnt0/wave)
      const unsigned tgt = (unsigned)(t0 + tl + 1);
      if (tid == 0)
        __hip_atomic_store(&flags[(size_t)wg * 16], tgt, __ATOMIC_RELAXED, __HIP_MEMORY_SCOPE_AGENT);
      // overlap: prefetch next step's xg + mask (immutable -> cache staleness ok)
      {
        const ushort* xp = xg + (size_t)(tl + 1) * BATCH * GH;
        xv0 = *(const ushort4*)(xp + (size_t)(b0 + bl0) * GH + (j0 + jjc) * 4);
        xv1 = *(const ushort4*)(xp + (size_t)(b0 + bl1) * GH + (j0 + jjc) * 4);
        m0v = (float)mask[(tl + 1) * BATCH + b0 + bl0];
        m1v = (float)mask[(tl + 1) * BATCH + b0 + bl1];
      }
      __builtin_amdgcn_sched_barrier(0);
      // leaders (wg<8): aggregate 32 member flags {wg, wg+8, ..., wg+248}
      if (wg < 8) {
        if (tid < 32) {
          for (;;) {
            unsigned v = __hip_atomic_load(&flags[(size_t)(wg + tid * 8) * 16],
                                           __ATOMIC_RELAXED, __HIP_MEMORY_SCOPE_AGENT);
            if (__all(v >= tgt)) break;
          }
        }
        if (tid == 0)
          __hip_atomic_store(&flags[(size_t)(NWG + wg) * 16], tgt,
                             __ATOMIC_RELAXED, __HIP_MEMORY_SCOPE_AGENT);
      }
      // everyone: poll the 8 leader flags
      if (tid < 8) {
        for (;;) {
          unsigned v = __hip_atomic_load(&flags[(size_t)(NWG + tid) * 16],
                                         __ATOMIC_RELAXED, __HIP_MEMORY_SCOPE_AGENT);
          if (__all(v >= tgt)) break;
        }
      }
      // single acquire -> buffer_inv: subsequent cached h loads refill from LLC
      if (tid == 0)
        (void)__hip_atomic_load(&flags[(size_t)NWG * 16], __ATOMIC_ACQUIRE, __HIP_MEMORY_SCOPE_AGENT);
      __syncthreads();
    }
    cur ^= 1;
  }
#undef CHUNK

  // persist cell state for next chunk
  cbuf[(size_t)(b0 + bl0) * HID + j0 + jjc] = creg0;
  cbuf[(size_t)(b0 + bl1) * HID + j0 + jjc] = creg1;
}

extern "C" void kernel_launch(void* const* d_in, const int* in_sizes, int n_in,
                              void* d_out, int out_size, void* d_ws, size_t ws_size,
                              hipStream_t stream) {
  (void)in_sizes; (void)n_in; (void)out_size;
  const float* state = (const float*)d_in[0];
  const int*   mask  = (const int*)d_in[1];
  const float* Wenc  = (const float*)d_in[2];
  const float* benc  = (const float*)d_in[3];
  const float* Wih   = (const float*)d_in[4];
  const float* Whh   = (const float*)d_in[5];
  const float* bih   = (const float*)d_in[6];
  const float* bhh   = (const float*)d_in[7];
  const float* Wdec  = (const float*)d_in[8];
  const float* bdec  = (const float*)d_in[9];

  float* out_values = (float*)d_out;                       // T*B*A
  float* out_h = out_values + (size_t)TBROWS * ACTD;       // B*H
  float* out_c = out_h + (size_t)BATCH * HID;              // B*H

  auto pad256 = [](size_t b) { return (b + 255) & ~(size_t)255; };

  const size_t sz_wenc  = (size_t)HID * OBSD * 2;
  const size_t sz_wih   = (size_t)GH * HID * 2;
  const size_t sz_whh   = (size_t)GH * HID * 2;
  const size_t sz_wdec  = (size_t)128 * HID * 2;
  const size_t sz_bdec  = 512;
  const size_t sz_bperm = (size_t)GH * sizeof(float);
  const size_t sz_flags = (NWG + 8) * 16 * sizeof(unsigned);
  const size_t sz_hbuf  = (size_t)2 * BATCH * HID * 2;
  const size_t sz_cbuf  = (size_t)BATCH * HID * 4;
  const size_t fixed = pad256(sz_wenc) + pad256(sz_wih) + pad256(sz_whh) +
                       pad256(sz_wdec) + pad256(sz_bdec) + pad256(sz_bperm) +
                       pad256(sz_flags) + pad256(sz_hbuf) + pad256(sz_cbuf);

  int Tc = 8;
  {
    const int cands[6] = {256, 128, 64, 32, 16, 8};
    for (int ci = 0; ci < 6; ++ci) {
      int tc = cands[ci];
      size_t per = pad256((size_t)tc * BATCH * OBSD * 2)
                 + pad256((size_t)tc * BATCH * HID * 2)
                 + pad256((size_t)tc * BATCH * GH * 2)
                 + pad256((size_t)tc * BATCH * HID * 2);
      if (fixed + per <= ws_size) { Tc = tc; break; }
    }
  }
  const int nchunks = T_STEPS / Tc;
  const int crows = Tc * BATCH;

  char* ws = (char*)d_ws;
  size_t off = 0;
  auto alloc = [&](size_t b) { char* r = ws + off; off += pad256(b); return r; };
  ushort* wenc_bf  = (ushort*)alloc(sz_wenc);
  ushort* wih_perm = (ushort*)alloc(sz_wih);
  ushort* whh_bf   = (ushort*)alloc(sz_whh);
  ushort* wdec_pad = (ushort*)alloc(sz_wdec);
  float*  bdec_pad = (float*)alloc(sz_bdec);
  float*  bperm    = (float*)alloc(sz_bperm);
  unsigned* flags  = (unsigned*)alloc(sz_flags);
  ushort* hbuf     = (ushort*)alloc(sz_hbuf);
  float*  cbuf     = (float*)alloc(sz_cbuf);
  ushort* state_c  = (ushort*)alloc((size_t)crows * OBSD * 2);
  ushort* enc_c    = (ushort*)alloc((size_t)crows * HID * 2);
  ushort* xg_c     = (ushort*)alloc((size_t)crows * GH * 2);
  ushort* lat_c    = (ushort*)alloc((size_t)crows * HID * 2);

  hipMemsetAsync(hbuf, 0, sz_hbuf, stream);
  hipMemsetAsync(flags, 0, sz_flags, stream);
  hipMemsetAsync(wdec_pad, 0, sz_wdec, stream);
  hipMemsetAsync(bdec_pad, 0, sz_bdec, stream);
  hipMemcpyAsync(bdec_pad, bdec, ACTD * sizeof(float), hipMemcpyDeviceToDevice, stream);

  auto cast = [&](const float* src, ushort* dst, size_t n) {
    int n4 = (int)(n / 4);
    int blocks = (n4 + 255) / 256;
    if (blocks > 4096) blocks = 4096;
    cast_bf16_kernel<<<blocks, 256, 0, stream>>>(src, dst, n4);
  };
  cast(Wenc, wenc_bf, (size_t)HID * OBSD);
  cast(Whh, whh_bf, (size_t)GH * HID);
  cast(Wdec, wdec_pad, (size_t)ACTD * HID);
  cast_permute_wih_kernel<<<(GH * 128) / 256, 256, 0, stream>>>(Wih, wih_perm);
  bias_perm_kernel<<<GH / 256, 256, 0, stream>>>(bih, bhh, bperm);

  for (int c = 0; c < nchunks; ++c) {
    const int t0 = c * Tc;
    cast(state + (size_t)t0 * BATCH * OBSD, state_c, (size_t)crows * OBSD);
    // encode: relu(state @ Wenc^T + b_enc)
    gemm_bt_kernel<<<(crows / 128) * (HID / 128), 256, 0, stream>>>(
        state_c, wenc_bf, benc, nullptr, enc_c, crows, HID, OBSD, 1, nullptr, nullptr);
    // x-gates (gate-permuted cols): enc @ Wih_perm^T + bperm
    gemm_bt_kernel<<<(crows / 128) * (GH / 128), 256, 0, stream>>>(
        enc_c, wih_perm, bperm, nullptr, xg_c, crows, GH, HID, 0, nullptr, nullptr);
    // sequential scan over this chunk
    lstm_scan_kernel<<<NWG, 256, 0, stream>>>(
        xg_c, whh_bf, mask + (size_t)t0 * BATCH, hbuf, lat_c, cbuf,
        out_h, out_c, flags, t0, Tc);
    // fused decode + mask + extract
    gemm_bt_kernel<<<crows / 128, 256, 0, stream>>>(
        lat_c, wdec_pad, bdec_pad, nullptr, nullptr, crows, 128, HID, 0,
        mask + (size_t)t0 * BATCH, out_values + (size_t)t0 * BATCH * ACTD);
  }
}

// Round 7
// 1641.002 us; speedup vs baseline: 4.0182x; 1.3680x over previous
//
#include <hip/hip_runtime.h>

#define T_STEPS 256
#define BATCH   128
#define OBSD    512
#define HID     1024
#define GH      4096
#define ACTD    18
#define TBROWS  (T_STEPS*BATCH)   // 32768
#define NWG     256               // scan WGs: 4 batch quarters x 64 j-slices
#define JG      16                // hidden units per scan WG

typedef __bf16 bf16x8_t __attribute__((ext_vector_type(8)));
typedef float  f32x4_t  __attribute__((ext_vector_type(4)));

__device__ __forceinline__ ushort f2bf(float f) {
  unsigned u = __builtin_bit_cast(unsigned, f);
  u += 0x7fffu + ((u >> 16) & 1u);          // RNE
  return (ushort)(u >> 16);
}
__device__ __forceinline__ float bf2f(ushort s) {
  return __builtin_bit_cast(float, ((unsigned)s) << 16);
}
__device__ __forceinline__ f32x4_t mfma16(bf16x8_t a, bf16x8_t b, f32x4_t c) {
  return __builtin_amdgcn_mfma_f32_16x16x32_bf16(a, b, c, 0, 0, 0);
}
__device__ __forceinline__ void gl_lds16(const void* g, void* l) {
  __builtin_amdgcn_global_load_lds(
      (__attribute__((address_space(1))) void*)(g),
      (__attribute__((address_space(3))) void*)(l), 16, 0, 0);
}
// agent-coherent staging load: sc0|sc1 (CPol 1|16) -> bypass L1/L2, read LLC
__device__ __forceinline__ void gl_lds16_cc(const void* g, void* l) {
  __builtin_amdgcn_global_load_lds(
      (__attribute__((address_space(1))) void*)(g),
      (__attribute__((address_space(3))) void*)(l), 16, 0, 17);
}
__device__ __forceinline__ float sigm(float x) { return 1.f / (1.f + __expf(-x)); }
__device__ __forceinline__ float tanhf_fast(float x) {
  float e = __expf(2.f * x);
  return (e - 1.f) / (e + 1.f);
}
// vmcnt-only wait (lgkm=15/exp=7 fields = no-wait)
__device__ __forceinline__ void wait_vm0() { __builtin_amdgcn_s_waitcnt(0x0F70); }

// ---------------- cast f32 -> bf16 ----------------
__global__ void cast_bf16_kernel(const float* __restrict__ in, ushort* __restrict__ out, int n4) {
  int i = blockIdx.x * blockDim.x + threadIdx.x;
  int stride = gridDim.x * blockDim.x;
  for (; i < n4; i += stride) {
    float4 v = reinterpret_cast<const float4*>(in)[i];
    ushort4 o;
    o.x = f2bf(v.x); o.y = f2bf(v.y); o.z = f2bf(v.z); o.w = f2bf(v.w);
    reinterpret_cast<ushort4*>(out)[i] = o;
  }
}

// ---------------- cast+permute W_ih: dst row hid*4+g <- src row g*HID+hid ----------------
__global__ void cast_permute_wih_kernel(const float* __restrict__ in, ushort* __restrict__ out) {
  int idx = blockIdx.x * 256 + threadIdx.x;     // over 4096 * 128
  int rowd = idx >> 7;
  int c8 = (idx & 127) << 3;
  int g = rowd & 3, hid = rowd >> 2;
  const float* src = in + ((size_t)g * HID + hid) * HID + c8;
  ushort* dst = out + (size_t)rowd * HID + c8;
#pragma unroll
  for (int i = 0; i < 8; ++i) dst[i] = f2bf(src[i]);
}

// ---------------- bias permute: out[hid*4+g] = bih[g*H+hid] + bhh[g*H+hid] ----------------
__global__ void bias_perm_kernel(const float* __restrict__ bih, const float* __restrict__ bhh,
                                 float* __restrict__ out) {
  int i = blockIdx.x * 256 + threadIdx.x;       // 4096
  int g = i & 3, hid = i >> 2;
  out[i] = bih[g * HID + hid] + bhh[g * HID + hid];
}

// ---------------- bf16 GEMM: C = act(A @ Bt^T + bias1 [+ bias2]) ----------------
// 128x128 tile, BK=64, 4 waves (2x2), m97 structure. XCD-swizzled blockIdx.
// If ovals != nullptr: fused decode epilogue (f32, masked, cols < ACTD; N==128).
__global__ __launch_bounds__(256) void gemm_bt_kernel(
    const ushort* __restrict__ A, const ushort* __restrict__ Bt,
    const float* __restrict__ bias1, const float* __restrict__ bias2,
    ushort* __restrict__ C, int M, int N, int K, int relu,
    const int* __restrict__ omask, float* __restrict__ ovals)
{
  __shared__ ushort la[128 * 64];   // 16 KB
  __shared__ ushort lb[128 * 64];   // 16 KB

  const int tid  = threadIdx.x;
  const int lane = tid & 63;
  const int w    = tid >> 6;
  const int wm   = w >> 1, wn = w & 1;
  const int nwg = gridDim.x;
  const int q8  = nwg >> 3;
  const int bid = (blockIdx.x & 7) * q8 + (blockIdx.x >> 3);
  const int ntiles = N >> 7;
  const int bm = bid / ntiles, bn = bid % ntiles;
  const size_t m0 = (size_t)bm << 7, n0 = (size_t)bn << 7;

  const int lrow = lane & 15;
  const int lk   = (lane >> 4) << 3;
  const int wavebase = (tid & ~63);

  f32x4_t acc[4][4];
  const f32x4_t zero = {0.f, 0.f, 0.f, 0.f};
#pragma unroll
  for (int i = 0; i < 4; ++i)
#pragma unroll
    for (int j = 0; j < 4; ++j) acc[i][j] = zero;

  for (int k0 = 0; k0 < K; k0 += 64) {
#pragma unroll
    for (int p = 0; p < 4; ++p) {
      int c = p * 256 + tid;
      int r = c >> 3;
      int q = (c & 7) << 3;
      gl_lds16(A + (m0 + r) * (size_t)K + k0 + q, la + (size_t)(p * 256 + wavebase) * 8);
      gl_lds16(Bt + (n0 + r) * (size_t)K + k0 + q, lb + (size_t)(p * 256 + wavebase) * 8);
    }
    __syncthreads();
#pragma unroll
    for (int kk = 0; kk < 64; kk += 32) {
      bf16x8_t af[4], bfr[4];
#pragma unroll
      for (int i = 0; i < 4; ++i)
        af[i] = *(const bf16x8_t*)(la + (wm * 64 + i * 16 + lrow) * 64 + kk + lk);
#pragma unroll
      for (int j = 0; j < 4; ++j)
        bfr[j] = *(const bf16x8_t*)(lb + (wn * 64 + j * 16 + lrow) * 64 + kk + lk);
#pragma unroll
      for (int i = 0; i < 4; ++i)
#pragma unroll
        for (int j = 0; j < 4; ++j)
          acc[i][j] = mfma16(af[i], bfr[j], acc[i][j]);
    }
    __syncthreads();
  }

  const int crow0 = (lane >> 4) * 4;
  if (ovals) {
#pragma unroll
    for (int j = 0; j < 4; ++j) {
      int col = wn * 64 + j * 16 + lrow;
      if (col < ACTD) {
        float bv = bias1[col];
#pragma unroll
        for (int i = 0; i < 4; ++i) {
#pragma unroll
          for (int r = 0; r < 4; ++r) {
            size_t row = m0 + wm * 64 + i * 16 + crow0 + r;
            float mv = (float)omask[row];
            ovals[row * ACTD + col] = (acc[i][j][r] + bv) * mv;
          }
        }
      }
    }
    return;
  }
#pragma unroll
  for (int j = 0; j < 4; ++j) {
    int col = (int)n0 + wn * 64 + j * 16 + lrow;
    float bv = bias1 ? bias1[col] : 0.f;
    if (bias2) bv += bias2[col];
#pragma unroll
    for (int i = 0; i < 4; ++i) {
#pragma unroll
      for (int r = 0; r < 4; ++r) {
        size_t row = m0 + wm * 64 + i * 16 + crow0 + r;
        float v = acc[i][j][r] + bv;
        if (relu) v = fmaxf(v, 0.f);
        C[row * (size_t)N + col] = f2bf(v);
      }
    }
  }
}

// ---------------- persistent LSTM scan (chunk [t0, t0+nsteps)) ----------------
// 256 WGs = 4 batch quarters x 64 j-slices (16 hidden each).
// r6: W_hh fragments in registers (af[8][4]); 128 KB LDS reused as 8x8KB staging;
//     all 16 global_load_lds issued up-front, consumed with counted vmcnt.
// r7: (a) quarters are fully independent -> PER-QUARTER flat depth-1 barrier
//     (64 flags, one per lane of wave0); (b) staging loads are agent-coherent
//     (sc0|sc1 -> read LLC directly), so the per-step acquire/buffer_inv is gone.
__global__ __launch_bounds__(256, 1) void lstm_scan_kernel(
    const ushort* __restrict__ xg,      // (nsteps,B,4H) bf16, gate-permuted
    const ushort* __restrict__ whh,     // (4H,H) bf16 natural
    const int* __restrict__ mask,       // (nsteps,B) (pre-offset)
    ushort* __restrict__ hbuf,          // (2,B,H) bf16 (zeroed at start)
    ushort* __restrict__ latent,        // (nsteps,B,H) bf16
    float* __restrict__ cbuf,           // (B,H) f32 persistent cell state
    float* __restrict__ outh, float* __restrict__ outc,   // (B,H) f32
    unsigned* __restrict__ flags,       // 256 x 16 uints, zeroed per launch
    int t0, int nsteps)
{
  __shared__ __align__(16) ushort lds_pool[64 * 1024];  // 128 KB: W gather, then 8x8KB staging
  __shared__ __align__(16) ushort hexch[32 * 16];       // 1 KB h exchange bounce

  const int tid  = threadIdx.x;
  const int lane = tid & 63;
  const int w    = tid >> 6;
  const int wg   = blockIdx.x;
  const int bq   = wg >> 6;            // batch quarter 0..3
  const int jg   = wg & 63;            // j slice
  const int j0   = jg * JG;
  const int b0   = bq * 32;

  const int lrow = lane & 15;
  const int lkg  = lane >> 4;

  // ---- phase A: gather W_hh slice into LDS (row rr = jj*4+g, granule-swizzled) ----
  for (int c = tid; c < 64 * 128; c += 256) {
    int r = c >> 7, gn = c & 127;
    int jj = r >> 2, g = r & 3;
    const ushort* src = whh + ((size_t)g * HID + j0 + jj) * HID + gn * 8;
    int gnd = (gn & ~7) | ((gn & 7) ^ (r & 7));
    *reinterpret_cast<uint4*>(&lds_pool[r * 1024 + gnd * 8]) =
        *reinterpret_cast<const uint4*>(src);
  }
  __syncthreads();

  // ---- phase B: extract this wave's A-fragments to registers (128 regs/lane) ----
  bf16x8_t af[8][4];
#pragma unroll
  for (int kc = 0; kc < 8; ++kc) {
#pragma unroll
    for (int ks = 0; ks < 4; ++ks) {
      int gA = kc * 16 + ks * 4 + lkg;
      int gAs = (gA & ~7) | ((gA & 7) ^ (lrow & 7));
      af[kc][ks] = *(const bf16x8_t*)(lds_pool + (size_t)(w * 16 + lrow) * 1024 + gAs * 8);
    }
  }
  __syncthreads();                      // all reads done before staging overwrites
  ushort* hstg = lds_pool;              // 8 buffers x 4096 ushorts (64 KB used)

  // cell mapping: jjc = w*4+lkg; local batch rows bl0 = lrow, bl1 = 16+lrow
  const int jjc = w * 4 + lkg;
  const int bl0 = lrow, bl1 = 16 + lrow;

  float creg0, creg1;
  if (t0 == 0) { creg0 = creg1 = 0.f; }
  else {
    creg0 = cbuf[(size_t)(b0 + bl0) * HID + j0 + jjc];
    creg1 = cbuf[(size_t)(b0 + bl1) * HID + j0 + jjc];
  }

  int cur = t0 & 1;

  // staging DMA constants: slots s0 = w*128+lane (instr0), s1 = s0+64 (instr1)
  const int s0 = w * 128 + lane;
  const int s1 = s0 + 64;
  const int sb0 = s0 >> 4, sq0 = s0 & 15;
  const int sb1 = s1 >> 4, sq1 = s1 & 15;
  const int gg0 = (sq0 & 8) | ((sq0 & 7) ^ (sb0 & 7));   // source granule (swizzle inverse)
  const int gg1 = (sq1 & 8) | ((sq1 & 7) ^ (sb1 & 7));

  // per-quarter flag pointer for the flat poll (lane i watches group flag i)
  const unsigned* fpoll = &flags[(size_t)(bq * 64 + lane) * 16];

  // prefetch xg/mask for step 0
  ushort4 xv0, xv1;
  float m0v, m1v;
  {
    xv0 = *(const ushort4*)(xg + (size_t)(b0 + bl0) * GH + (j0 + jjc) * 4);
    xv1 = *(const ushort4*)(xg + (size_t)(b0 + bl1) * GH + (j0 + jjc) * 4);
    m0v = (float)mask[b0 + bl0];
    m1v = (float)mask[b0 + bl1];
  }
  __builtin_amdgcn_sched_barrier(0);

#define CHUNK(KC, VN) do {                                                     \
    __builtin_amdgcn_s_waitcnt(0x0F70 | (VN));                                 \
    __builtin_amdgcn_s_barrier();                                              \
    __builtin_amdgcn_sched_barrier(0);                                         \
    const ushort* sbuf = hstg + (size_t)(KC) * 4096;                           \
    _Pragma("unroll")                                                          \
    for (int ks = 0; ks < 4; ++ks) {                                           \
      int q16 = ks * 4 + lkg;                                                  \
      int qs = (q16 & 8) | ((q16 & 7) ^ (bl0 & 7));                            \
      bf16x8_t bf0 = *(const bf16x8_t*)(sbuf + (size_t)bl0 * 128 + qs * 8);    \
      bf16x8_t bf1 = *(const bf16x8_t*)(sbuf + (size_t)bl1 * 128 + qs * 8);    \
      acc0 = mfma16(af[KC][ks], bf0, acc0);                                    \
      acc1 = mfma16(af[KC][ks], bf1, acc1);                                    \
    }                                                                          \
    __builtin_amdgcn_sched_barrier(0);                                         \
  } while (0)

  for (int tl = 0; tl < nsteps; ++tl) {
    const ushort* hsrc = hbuf + (size_t)cur * (BATCH * HID) + (size_t)b0 * HID;

    wait_vm0();                          // clean vmcnt slate
    __builtin_amdgcn_sched_barrier(0);

    f32x4_t acc0 = {0.f, 0.f, 0.f, 0.f};
    f32x4_t acc1 = {0.f, 0.f, 0.f, 0.f};

    // issue ALL 16 agent-coherent staging loads (8 chunks x 2) back-to-back
#pragma unroll
    for (int kc = 0; kc < 8; ++kc) {
      gl_lds16_cc(hsrc + (size_t)sb0 * HID + (kc * 16 + gg0) * 8,
                  hstg + (size_t)kc * 4096 + (size_t)(w * 128) * 8);
      gl_lds16_cc(hsrc + (size_t)sb1 * HID + (kc * 16 + gg1) * 8,
                  hstg + (size_t)kc * 4096 + (size_t)(w * 128 + 64) * 8);
    }
    __builtin_amdgcn_sched_barrier(0);

    CHUNK(0, 14); CHUNK(1, 12); CHUNK(2, 10); CHUNK(3, 8);
    CHUNK(4, 6);  CHUNK(5, 4);  CHUNK(6, 2);  CHUNK(7, 0);

    // ---- epilogue: fragment-native nonlinearities (lane owns 2 cells) ----
    {
      float ig = sigm(acc0[0] + bf2f(xv0.x));
      float fg = sigm(acc0[1] + bf2f(xv0.y));
      float gt = tanhf_fast(acc0[2] + bf2f(xv0.z));
      float og = sigm(acc0[3] + bf2f(xv0.w));
      float cp = fg * creg0 + ig * gt;
      creg0 = cp * m0v;
      float h0 = og * tanhf_fast(cp) * m0v;

      ig = sigm(acc1[0] + bf2f(xv1.x));
      fg = sigm(acc1[1] + bf2f(xv1.y));
      gt = tanhf_fast(acc1[2] + bf2f(xv1.z));
      og = sigm(acc1[3] + bf2f(xv1.w));
      cp = fg * creg1 + ig * gt;
      creg1 = cp * m1v;
      float h1 = og * tanhf_fast(cp) * m1v;

      ushort hb0 = f2bf(h0), hb1 = f2bf(h1);
      // bounce h through LDS for coalesced 8B coherent stores
      hexch[bl0 * 16 + jjc] = hb0;
      hexch[bl1 * 16 + jjc] = hb1;
      // latent: normal cached stores (read only after kernel end)
      ushort* ldst = latent + (size_t)tl * BATCH * HID;
      ldst[(size_t)(b0 + bl0) * HID + j0 + jjc] = hb0;
      ldst[(size_t)(b0 + bl1) * HID + j0 + jjc] = hb1;
      if (t0 + tl == T_STEPS - 1) {
        outh[(size_t)(b0 + bl0) * HID + j0 + jjc] = h0;
        outh[(size_t)(b0 + bl1) * HID + j0 + jjc] = h1;
        outc[(size_t)(b0 + bl0) * HID + j0 + jjc] = creg0;
        outc[(size_t)(b0 + bl1) * HID + j0 + jjc] = creg1;
      }
    }
    __syncthreads();                     // hexch complete (lgkm)

    // device-coherent 8B h stores (write-through to LLC, no fence needed)
    if (tid < 128) {
      int bl = tid >> 2, seg = tid & 3;
      unsigned long long v = *(const unsigned long long*)(&hexch[bl * 16 + seg * 4]);
      unsigned long long* dst = (unsigned long long*)(hbuf +
          (size_t)(cur ^ 1) * (BATCH * HID) + (size_t)(b0 + bl) * HID + j0 + seg * 4);
      __hip_atomic_store(dst, v, __ATOMIC_RELAXED, __HIP_MEMORY_SCOPE_AGENT);
    }

    // ---- per-quarter flat depth-1 barrier (skip after last local step) ----
    if (tl != nsteps - 1) {
      __syncthreads();                   // all h atomic stores complete (vmcnt0/wave)
      const unsigned tgt = (unsigned)(t0 + tl + 1);
      if (tid == 0)
        __hip_atomic_store(&flags[(size_t)wg * 16], tgt, __ATOMIC_RELAXED, __HIP_MEMORY_SCOPE_AGENT);
      // overlap: prefetch next step's xg + mask (immutable -> cache staleness ok)
      {
        const ushort* xp = xg + (size_t)(tl + 1) * BATCH * GH;
        xv0 = *(const ushort4*)(xp + (size_t)(b0 + bl0) * GH + (j0 + jjc) * 4);
        xv1 = *(const ushort4*)(xp + (size_t)(b0 + bl1) * GH + (j0 + jjc) * 4);
        m0v = (float)mask[(tl + 1) * BATCH + b0 + bl0];
        m1v = (float)mask[(tl + 1) * BATCH + b0 + bl1];
      }
      __builtin_amdgcn_sched_barrier(0);
      // wave0: lane i polls group flag i (64 flags, one LLC trip per sweep)
      if (tid < 64) {
        for (;;) {
          unsigned v = __hip_atomic_load(fpoll, __ATOMIC_RELAXED, __HIP_MEMORY_SCOPE_AGENT);
          if (__all(v >= tgt)) break;
        }
      }
      __syncthreads();
    }
    cur ^= 1;
  }
#undef CHUNK

  // persist cell state for next chunk
  cbuf[(size_t)(b0 + bl0) * HID + j0 + jjc] = creg0;
  cbuf[(size_t)(b0 + bl1) * HID + j0 + jjc] = creg1;
}

extern "C" void kernel_launch(void* const* d_in, const int* in_sizes, int n_in,
                              void* d_out, int out_size, void* d_ws, size_t ws_size,
                              hipStream_t stream) {
  (void)in_sizes; (void)n_in; (void)out_size;
  const float* state = (const float*)d_in[0];
  const int*   mask  = (const int*)d_in[1];
  const float* Wenc  = (const float*)d_in[2];
  const float* benc  = (const float*)d_in[3];
  const float* Wih   = (const float*)d_in[4];
  const float* Whh   = (const float*)d_in[5];
  const float* bih   = (const float*)d_in[6];
  const float* bhh   = (const float*)d_in[7];
  const float* Wdec  = (const float*)d_in[8];
  const float* bdec  = (const float*)d_in[9];

  float* out_values = (float*)d_out;                       // T*B*A
  float* out_h = out_values + (size_t)TBROWS * ACTD;       // B*H
  float* out_c = out_h + (size_t)BATCH * HID;              // B*H

  auto pad256 = [](size_t b) { return (b + 255) & ~(size_t)255; };

  const size_t sz_wenc  = (size_t)HID * OBSD * 2;
  const size_t sz_wih   = (size_t)GH * HID * 2;
  const size_t sz_whh   = (size_t)GH * HID * 2;
  const size_t sz_wdec  = (size_t)128 * HID * 2;
  const size_t sz_bdec  = 512;
  const size_t sz_bperm = (size_t)GH * sizeof(float);
  const size_t sz_flags = NWG * 16 * sizeof(unsigned);
  const size_t sz_hbuf  = (size_t)2 * BATCH * HID * 2;
  const size_t sz_cbuf  = (size_t)BATCH * HID * 4;
  const size_t fixed = pad256(sz_wenc) + pad256(sz_wih) + pad256(sz_whh) +
                       pad256(sz_wdec) + pad256(sz_bdec) + pad256(sz_bperm) +
                       pad256(sz_flags) + pad256(sz_hbuf) + pad256(sz_cbuf);

  int Tc = 8;
  {
    const int cands[6] = {256, 128, 64, 32, 16, 8};
    for (int ci = 0; ci < 6; ++ci) {
      int tc = cands[ci];
      size_t per = pad256((size_t)tc * BATCH * OBSD * 2)
                 + pad256((size_t)tc * BATCH * HID * 2)
                 + pad256((size_t)tc * BATCH * GH * 2)
                 + pad256((size_t)tc * BATCH * HID * 2);
      if (fixed + per <= ws_size) { Tc = tc; break; }
    }
  }
  const int nchunks = T_STEPS / Tc;
  const int crows = Tc * BATCH;

  char* ws = (char*)d_ws;
  size_t off = 0;
  auto alloc = [&](size_t b) { char* r = ws + off; off += pad256(b); return r; };
  ushort* wenc_bf  = (ushort*)alloc(sz_wenc);
  ushort* wih_perm = (ushort*)alloc(sz_wih);
  ushort* whh_bf   = (ushort*)alloc(sz_whh);
  ushort* wdec_pad = (ushort*)alloc(sz_wdec);
  float*  bdec_pad = (float*)alloc(sz_bdec);
  float*  bperm    = (float*)alloc(sz_bperm);
  unsigned* flags  = (unsigned*)alloc(sz_flags);
  ushort* hbuf     = (ushort*)alloc(sz_hbuf);
  float*  cbuf     = (float*)alloc(sz_cbuf);
  ushort* state_c  = (ushort*)alloc((size_t)crows * OBSD * 2);
  ushort* enc_c    = (ushort*)alloc((size_t)crows * HID * 2);
  ushort* xg_c     = (ushort*)alloc((size_t)crows * GH * 2);
  ushort* lat_c    = (ushort*)alloc((size_t)crows * HID * 2);

  hipMemsetAsync(hbuf, 0, sz_hbuf, stream);
  hipMemsetAsync(flags, 0, sz_flags, stream);
  hipMemsetAsync(wdec_pad, 0, sz_wdec, stream);
  hipMemsetAsync(bdec_pad, 0, sz_bdec, stream);
  hipMemcpyAsync(bdec_pad, bdec, ACTD * sizeof(float), hipMemcpyDeviceToDevice, stream);

  auto cast = [&](const float* src, ushort* dst, size_t n) {
    int n4 = (int)(n / 4);
    int blocks = (n4 + 255) / 256;
    if (blocks > 4096) blocks = 4096;
    cast_bf16_kernel<<<blocks, 256, 0, stream>>>(src, dst, n4);
  };
  cast(Wenc, wenc_bf, (size_t)HID * OBSD);
  cast(Whh, whh_bf, (size_t)GH * HID);
  cast(Wdec, wdec_pad, (size_t)ACTD * HID);
  cast_permute_wih_kernel<<<(GH * 128) / 256, 256, 0, stream>>>(Wih, wih_perm);
  bias_perm_kernel<<<GH / 256, 256, 0, stream>>>(bih, bhh, bperm);

  for (int c = 0; c < nchunks; ++c) {
    const int t0 = c * Tc;
    cast(state + (size_t)t0 * BATCH * OBSD, state_c, (size_t)crows * OBSD);
    // encode: relu(state @ Wenc^T + b_enc)
    gemm_bt_kernel<<<(crows / 128) * (HID / 128), 256, 0, stream>>>(
        state_c, wenc_bf, benc, nullptr, enc_c, crows, HID, OBSD, 1, nullptr, nullptr);
    // x-gates (gate-permuted cols): enc @ Wih_perm^T + bperm
    gemm_bt_kernel<<<(crows / 128) * (GH / 128), 256, 0, stream>>>(
        enc_c, wih_perm, bperm, nullptr, xg_c, crows, GH, HID, 0, nullptr, nullptr);
    // sequential scan over this chunk
    lstm_scan_kernel<<<NWG, 256, 0, stream>>>(
        xg_c, whh_bf, mask + (size_t)t0 * BATCH, hbuf, lat_c, cbuf,
        out_h, out_c, flags, t0, Tc);
    // fused decode + mask + extract
    gemm_bt_kernel<<<crows / 128, 256, 0, stream>>>(
        lat_c, wdec_pad, bdec_pad, nullptr, nullptr, crows, 128, HID, 0,
        mask + (size_t)t0 * BATCH, out_values + (size_t)t0 * BATCH * ACTD);
  }
}